// Round 10
// baseline (100.253 us; speedup 1.0000x reference)
//
#include <hip/hip_runtime.h>
#include <cstdint>

#define NB 32
#define NL 512
#define NE 256
#define NH 8
#define ND 64
#define NM 16384   // NB*NL
#define NHD 512    // NH*ND

using half8  = __attribute__((ext_vector_type(8))) _Float16;
using half4  = __attribute__((ext_vector_type(4))) _Float16;
using f32x4  = __attribute__((ext_vector_type(4))) float;
using f32x16 = __attribute__((ext_vector_type(16))) float;
using u32x2  = __attribute__((ext_vector_type(2))) unsigned int;

__device__ __forceinline__ f32x4 mfma16(half8 a, half8 b, f32x4 c) {
    return __builtin_amdgcn_mfma_f32_16x16x32_f16(a, b, c, 0, 0, 0);
}
__device__ __forceinline__ f32x16 mfma32(half8 a, half8 b, f32x16 c) {
    return __builtin_amdgcn_mfma_f32_32x32x16_f16(a, b, c, 0, 0, 0);
}
// async global->LDS, 16B/lane; LDS dest = wave-uniform base + lane*16.
__device__ __forceinline__ void cp16_g2l(const void* g, void* l) {
    __builtin_amdgcn_global_load_lds(
        (const __attribute__((address_space(1))) void*)g,
        (__attribute__((address_space(3))) void*)l, 16, 0, 0);
}
// 2^x on the TRANS pipe (v_exp_f32), no libm dependence.
__device__ __forceinline__ float exp2fast(float x) {
    return __builtin_amdgcn_exp2f(x);
}
// fast tanh: ~6 ops, 2 on TRANS pipe. |err| ~1e-6, invisible under f16.
__device__ __forceinline__ float fast_tanh(float x) {
    float xc = fminf(fmaxf(x, -9.f), 9.f);
    float t = exp2fast(xc * 2.88539008178f);   // e^(2x) = 2^(2x*log2e)
    return (t - 1.f) * __builtin_amdgcn_rcpf(t + 1.f);
}
// pack two f32 -> two f16 in one u32 (v_cvt_pkrtz_f16_f32)
__device__ __forceinline__ uint32_t pk16(float a, float b) {
    auto h2 = __builtin_amdgcn_cvt_pkrtz(a, b);
    return __builtin_bit_cast(uint32_t, h2);
}

// ---------------- K0: weight repack to f16, K-contiguous (1 MB total) -------
__global__ __launch_bounds__(256) void prep(
        const float* __restrict__ Wq, const float* __restrict__ Wk,
        const float* __restrict__ Wv, const float* __restrict__ Wo,
        _Float16* __restrict__ wqkv, _Float16* __restrict__ woh) {
    int idx = blockIdx.x * 256 + threadIdx.x;
    if (idx < 1536 * 256) {
        int n = idx >> 8, e = idx & 255;
        int s = n >> 9, h = (n >> 6) & 7, d = n & 63;
        const float* W = (s == 0) ? Wq : (s == 1) ? Wk : Wv;
        wqkv[idx] = (_Float16)W[(h * NE + e) * ND + d];
    } else {
        int j = idx - 1536 * 256;
        int e = j >> 9, f = j & 511;
        woh[j] = (_Float16)Wo[f * NE + e];
    }
}

// ---------------- K1: fused QKV projection GEMM ----------------
// B operand (xph) built on the fly from fp32 x+pos: reg-stage (T14 split:
// loads issued before compute, cvt+swizzled ds_write after) -- no xph buffer.
// A via global_load_lds (pre-swizzled source). BK=64, dbuf, 2-phase pipeline.
// q,k (tn<8): tanh -> [token][c]; v (tn>=8): operand-swap -> vT[c][token].
// Grid: XCD-chunked bijective remap (1536 = 8 x 12 x 16).
__global__ __launch_bounds__(256) void proj_gemm(
        const _Float16* __restrict__ wqkv, const float* __restrict__ x,
        const float* __restrict__ pos,
        _Float16* __restrict__ q_all, _Float16* __restrict__ k_all,
        _Float16* __restrict__ vT) {
    __shared__ _Float16 Alds[2][128 * 64];
    __shared__ _Float16 Blds[2][128 * 64];
    int tid = threadIdx.x;
    int w = tid >> 6, l = tid & 63;
    int bid = blockIdx.x;
    int xcd = bid & 7, local = bid >> 3;        // local in [0,192)
    int tn = local % 12;
    int tm = xcd * 16 + local / 12;             // contiguous tm chunk per XCD
    int wn = w >> 1, wm = w & 1;
    int m16 = l & 15, g = l >> 4;
    bool isv = (tn >= 8);
    int lrow8 = l >> 3;             // row within 8-row chunk (A staging)
    int kc16 = (l & 7) ^ lrow8;     // pre-swizzled global 16B k-unit (A)
    int br = tid >> 2;              // B staging: row 0..63 (+64 on pass 1)
    int bc = tid & 3;               // B staging: 16-f32 chunk (64B)
    f32x4 acc[4][4] = {};

    const _Float16* Ag = wqkv + (size_t)tn * 128 * 256;
    const float* Xg = x + (size_t)(tm * 128) * 256;
    const float* Pg = pos + (size_t)((tm & 3) * 128) * 256;

    float4 xr[2][4], pr[2][4];
#define PROJ_LOADB(kt)                                                        \
    _Pragma("unroll") for (int p = 0; p < 2; ++p) {                           \
        int row = p * 64 + br;                                                \
        const float* xp = Xg + (size_t)row * 256 + (kt) * 64 + bc * 16;       \
        const float* pp = Pg + (size_t)row * 256 + (kt) * 64 + bc * 16;       \
        _Pragma("unroll") for (int j = 0; j < 4; ++j) {                       \
            xr[p][j] = *(const float4*)(xp + j * 4);                          \
            pr[p][j] = *(const float4*)(pp + j * 4);                          \
        }                                                                     \
    }
#define PROJ_WRITEB(buf)                                                      \
    _Pragma("unroll") for (int p = 0; p < 2; ++p) {                           \
        int row = p * 64 + br;                                                \
        _Pragma("unroll") for (int c2 = 0; c2 < 2; ++c2) {                    \
            half8 hv;                                                         \
            _Pragma("unroll") for (int e = 0; e < 8; ++e) {                   \
                const float* xf = (const float*)&xr[p][c2 * 2 + (e >> 2)];    \
                const float* pf = (const float*)&pr[p][c2 * 2 + (e >> 2)];    \
                hv[e] = (_Float16)(xf[e & 3] + pf[e & 3]);                    \
            }                                                                 \
            int unit = bc * 2 + c2;                                           \
            *(half8*)(&Blds[buf][row * 64 + ((unit ^ (row & 7)) << 3)]) = hv; \
        }                                                                     \
    }
#define PROJ_STAGE_A(kt, buf)                                                 \
    _Pragma("unroll") for (int i = 0; i < 4; ++i) {                           \
        int cA = w * 4 + i;                                                   \
        int row = cA * 8 + lrow8;                                             \
        cp16_g2l(Ag + (size_t)row * 256 + (kt) * 64 + kc16 * 8,               \
                 &Alds[buf][cA * 512]);                                       \
    }

    PROJ_LOADB(0);
    PROJ_STAGE_A(0, 0);
    PROJ_WRITEB(0);
    __syncthreads();
    int cur = 0;
    for (int kt = 0; kt < 4; ++kt) {
        if (kt < 3) { PROJ_LOADB(kt + 1); PROJ_STAGE_A(kt + 1, cur ^ 1); }
#pragma unroll
        for (int ks = 0; ks < 2; ++ks) {
            half8 af[4], bf[4];
#pragma unroll
            for (int f = 0; f < 4; ++f) {
                int ra = wn * 64 + f * 16 + m16;
                int rb = wm * 64 + f * 16 + m16;
                af[f] = *(const half8*)(&Alds[cur][ra * 64 + (((ks * 4 + g) ^ (ra & 7)) << 3)]);
                bf[f] = *(const half8*)(&Blds[cur][rb * 64 + (((ks * 4 + g) ^ (rb & 7)) << 3)]);
            }
            if (!isv) {
#pragma unroll
                for (int nf = 0; nf < 4; ++nf)
#pragma unroll
                    for (int mf = 0; mf < 4; ++mf)
                        acc[nf][mf] = mfma16(af[nf], bf[mf], acc[nf][mf]);
            } else {
#pragma unroll
                for (int nf = 0; nf < 4; ++nf)
#pragma unroll
                    for (int mf = 0; mf < 4; ++mf)
                        acc[nf][mf] = mfma16(bf[mf], af[nf], acc[nf][mf]);
            }
        }
        if (kt < 3) { PROJ_WRITEB(cur ^ 1); }
        __syncthreads();
        cur ^= 1;
    }
#undef PROJ_LOADB
#undef PROJ_WRITEB
#undef PROJ_STAGE_A
    if (!isv) {
        _Float16* dst = (tn < 4) ? q_all : k_all;
#pragma unroll
        for (int nf = 0; nf < 4; ++nf) {
            int c = (tn & 3) * 128 + wn * 64 + nf * 16 + g * 4;
#pragma unroll
            for (int mf = 0; mf < 4; ++mf) {
                int m = tm * 128 + wm * 64 + mf * 16 + m16;
                f32x4 v = acc[nf][mf];
                half4 hv;
#pragma unroll
                for (int r = 0; r < 4; ++r) hv[r] = (_Float16)fast_tanh(v[r]);
                *(half4*)(dst + (size_t)m * NHD + c) = hv;
            }
        }
    } else {
#pragma unroll
        for (int nf = 0; nf < 4; ++nf) {
            int c = (tn - 8) * 128 + wn * 64 + nf * 16 + m16;
#pragma unroll
            for (int mf = 0; mf < 4; ++mf) {
                int t0 = tm * 128 + wm * 64 + mf * 16 + g * 4;
                f32x4 v = acc[nf][mf];    // rows = tokens t0+r, col = c
                half4 hv;
#pragma unroll
                for (int r = 0; r < 4; ++r) hv[r] = (_Float16)fast_tanh(v[r]);
                *(half4*)(vT + (size_t)c * NM + t0) = hv;
            }
        }
    }
}

// ---------------- K2: flash attention, 32x32x16 MFMA ----------------
// (verified R9 structure; only change: max3-tree row max)
__global__ __launch_bounds__(256, 3) void attn_kernel(
        const _Float16* __restrict__ q_all, const _Float16* __restrict__ k_all,
        const _Float16* __restrict__ vT, _Float16* __restrict__ attn_out) {
    __shared__ _Float16 Klds[2][64 * 64];   // [key][d], unit^=(key&7)
    __shared__ _Float16 Vtlds[2][64 * 64];  // [d][key], unit^=(d&7)
    int tid = threadIdx.x;
    int w = tid >> 6, l = tid & 63;
    int l31 = l & 31, hi = l >> 5;
    int bid = blockIdx.x;
    int qt = bid & 3, h = (bid >> 2) & 7, b = bid >> 5;
    const float C1 = 0.125f * 1.44269504089f;   // scale * log2(e)

    int qbase = qt * 128 + w * 32;
    half8 qf[4];   // B operand: [q=l31][d = ks*16 + hi*8]
    {
        const _Float16* qp = q_all + (size_t)(b * NL + qbase + l31) * NHD + h * ND + hi * 8;
#pragma unroll
        for (int ks = 0; ks < 4; ++ks) qf[ks] = *(const half8*)(qp + ks * 16);
    }

    f32x16 acc_o[2] = {};
    float mrow = -1e30f, lrow = 0.f;

    int st_row = tid >> 2;          // K: key / Vt: d
    int st_u0 = (tid & 3) * 2;      // two 16B units per thread
    const _Float16* kg = k_all + (size_t)(b * NL + st_row) * NHD + h * ND + st_u0 * 8;
    const _Float16* vg = vT + (size_t)(h * ND + st_row) * NM + b * NL + st_u0 * 8;
    int so0 = st_row * 64 + ((st_u0 ^ (st_row & 7)) << 3);
    int so1 = st_row * 64 + (((st_u0 + 1) ^ (st_row & 7)) << 3);

    uint4 kv0 = *(const uint4*)(kg);
    uint4 kv1 = *(const uint4*)(kg + 8);
    uint4 vv0 = *(const uint4*)(vg);
    uint4 vv1 = *(const uint4*)(vg + 8);
    *(uint4*)&Klds[0][so0] = kv0;   *(uint4*)&Klds[0][so1] = kv1;
    *(uint4*)&Vtlds[0][so0] = vv0;  *(uint4*)&Vtlds[0][so1] = vv1;
    __syncthreads();

    for (int kt = 0; kt < 8; ++kt) {
        int cur = kt & 1;
        if (kt < 7) {   // issue next-tile loads early (hide under compute)
            const _Float16* kp = kg + (size_t)(kt + 1) * 64 * NHD;
            const _Float16* vp = vg + (kt + 1) * 64;
            kv0 = *(const uint4*)(kp);      kv1 = *(const uint4*)(kp + 8);
            vv0 = *(const uint4*)(vp);      vv1 = *(const uint4*)(vp + 8);
        }
        // S^T = K Q^T : acc_s[kb2] rows=keys, cols=q
        f32x16 acc_s[2] = {};
        __builtin_amdgcn_s_setprio(1);
#pragma unroll
        for (int ks = 0; ks < 4; ++ks)
#pragma unroll
            for (int kb2 = 0; kb2 < 2; ++kb2) {
                int key = kb2 * 32 + l31;
                half8 kb = *(const half8*)(&Klds[cur][key * 64 + (((ks * 2 + hi) ^ (key & 7)) << 3)]);
                acc_s[kb2] = mfma32(kb, qf[ks], acc_s[kb2]);
            }
        __builtin_amdgcn_s_setprio(0);
        // online softmax, q = l31 per lane; max via v_max3-fusable tree
        float mx = -1e30f;
#pragma unroll
        for (int kb2 = 0; kb2 < 2; ++kb2)
#pragma unroll
            for (int j = 0; j < 16; j += 4) {
                float a = fmaxf(fmaxf(acc_s[kb2][j], acc_s[kb2][j + 1]),
                                acc_s[kb2][j + 2]);
                mx = fmaxf(fmaxf(mx, a), acc_s[kb2][j + 3]);
            }
        mx = fmaxf(mx, __shfl_xor(mx, 32));
        mx *= 0.125f;
        if (!__all(mx <= mrow + 8.f)) {   // defer-max: rescale rarely fires
            float mn = fmaxf(mrow, mx);
            float alpha = exp2fast((mrow - mn) * 1.44269504089f);
            mrow = mn;
            lrow *= alpha;
            float aq[16];
#pragma unroll
            for (int c = 0; c < 4; ++c)
#pragma unroll
                for (int r = 0; r < 4; ++r)
                    aq[c * 4 + r] = __shfl(alpha, c * 8 + hi * 4 + r);
#pragma unroll
            for (int d2 = 0; d2 < 2; ++d2)
#pragma unroll
                for (int j = 0; j < 16; ++j) acc_o[d2][j] *= aq[j];
        }
        // p = exp2(fma(s, C1, -ml)); pack pairs to f16 words in regs
        float ml = mrow * 1.44269504089f;
        float rs = 0.f;
        uint32_t cw[2][4][2];
#pragma unroll
        for (int kb2 = 0; kb2 < 2; ++kb2)
#pragma unroll
            for (int a = 0; a < 4; ++a)
#pragma unroll
                for (int p = 0; p < 2; ++p) {
                    float p0 = exp2fast(fmaf(acc_s[kb2][4 * a + 2 * p],     C1, -ml));
                    float p1 = exp2fast(fmaf(acc_s[kb2][4 * a + 2 * p + 1], C1, -ml));
                    rs += p0 + p1;
                    cw[kb2][a][p] = pk16(p0, p1);
                }
        rs += __shfl_xor(rs, 32);
        lrow += rs;
        // O += P V   (pa assembled in-register via permlane32_swap)
        __builtin_amdgcn_s_setprio(1);
#pragma unroll
        for (int ks = 0; ks < 4; ++ks) {
            int kb2 = ks >> 1, s = ks & 1;
            u32x2 r0 = __builtin_amdgcn_permlane32_swap(
                cw[kb2][2 * s][0], cw[kb2][2 * s + 1][0], false, false);
            u32x2 r1 = __builtin_amdgcn_permlane32_swap(
                cw[kb2][2 * s][1], cw[kb2][2 * s + 1][1], false, false);
            union { uint32_t u[4]; half8 h; } pu;
            pu.u[0] = r0[0];  pu.u[1] = r1[0];   // e=0..3 (hi'=0 owner)
            pu.u[2] = r0[1];  pu.u[3] = r1[1];   // e=4..7 (hi'=1 owner)
#pragma unroll
            for (int d2 = 0; d2 < 2; ++d2) {
                int d = d2 * 32 + l31;
                half8 vb = *(const half8*)(&Vtlds[cur][d * 64 + (((ks * 2 + hi) ^ (d & 7)) << 3)]);
                acc_o[d2] = mfma32(pu.h, vb, acc_o[d2]);
            }
        }
        __builtin_amdgcn_s_setprio(0);
        if (kt < 7) {   // write prefetched tile, single barrier per tile
            int nxt = cur ^ 1;
            *(uint4*)&Klds[nxt][so0] = kv0;   *(uint4*)&Klds[nxt][so1] = kv1;
            *(uint4*)&Vtlds[nxt][so0] = vv0;  *(uint4*)&Vtlds[nxt][so1] = vv1;
            __syncthreads();
        }
    }
    // epilogue: O[q][d], rows q from reg mapping, col d = d2*32 + l31
    size_t orow0 = (size_t)(b * NL + qbase);
#pragma unroll
    for (int c = 0; c < 4; ++c)
#pragma unroll
        for (int r = 0; r < 4; ++r) {
            int qrow = c * 8 + hi * 4 + r;
            float inv = 1.f / __shfl(lrow, qrow);
#pragma unroll
            for (int d2 = 0; d2 < 2; ++d2)
                attn_out[(orow0 + qrow) * NHD + h * ND + d2 * 32 + l31] =
                    (_Float16)(acc_o[d2][c * 4 + r] * inv);
        }
}

// ---------------- K3: output projection + fp32 tanh residual ----------------
// tile 128e x 64m -> 512 blocks. BK=64, swizzled dbuf LDS, 2-phase pipeline.
__global__ __launch_bounds__(256) void final_gemm(
        const _Float16* __restrict__ woh, const _Float16* __restrict__ attn,
        const float* __restrict__ x, const float* __restrict__ pos,
        float* __restrict__ out) {
    __shared__ _Float16 Alds[2][128 * 64];
    __shared__ _Float16 Blds[2][64 * 64];
    int tid = threadIdx.x;
    int w = tid >> 6, l = tid & 63;
    int tn = blockIdx.x & 1, tm = blockIdx.x >> 1;
    int wn = w >> 1, wm = w & 1;
    int m16 = l & 15, g = l >> 4;
    int lrow8 = l >> 3;
    int kc16 = (l & 7) ^ lrow8;
    f32x4 acc[4][2] = {};

    const _Float16* Ag = woh + (size_t)tn * 128 * 512;
    const _Float16* Bg = attn + (size_t)tm * 64 * 512;

#define FIN_STAGE(kt, buf)                                                    \
    _Pragma("unroll") for (int i = 0; i < 4; ++i) {                           \
        int cA = w * 4 + i;                                                   \
        int row = cA * 8 + lrow8;                                             \
        cp16_g2l(Ag + (size_t)row * 512 + (kt) * 64 + kc16 * 8,               \
                 &Alds[buf][cA * 512]);                                       \
    }                                                                         \
    _Pragma("unroll") for (int i = 0; i < 2; ++i) {                           \
        int cB = w * 2 + i;                                                   \
        int row = cB * 8 + lrow8;                                             \
        cp16_g2l(Bg + (size_t)row * 512 + (kt) * 64 + kc16 * 8,               \
                 &Blds[buf][cB * 512]);                                       \
    }

    FIN_STAGE(0, 0);
    __syncthreads();
    int cur = 0;
    for (int kt = 0; kt < 8; ++kt) {
        if (kt < 7) { FIN_STAGE(kt + 1, cur ^ 1); }
#pragma unroll
        for (int ks = 0; ks < 2; ++ks) {
            half8 af[4], bf[2];
#pragma unroll
            for (int f = 0; f < 4; ++f) {
                int ra = wn * 64 + f * 16 + m16;
                af[f] = *(const half8*)(&Alds[cur][ra * 64 + (((ks * 4 + g) ^ (ra & 7)) << 3)]);
            }
#pragma unroll
            for (int f = 0; f < 2; ++f) {
                int rb = wm * 32 + f * 16 + m16;
                bf[f] = *(const half8*)(&Blds[cur][rb * 64 + (((ks * 4 + g) ^ (rb & 7)) << 3)]);
            }
#pragma unroll
            for (int nf = 0; nf < 4; ++nf)
#pragma unroll
                for (int mf = 0; mf < 2; ++mf)
                    acc[nf][mf] = mfma16(af[nf], bf[mf], acc[nf][mf]);
        }
        __syncthreads();
        cur ^= 1;
    }
#undef FIN_STAGE
#pragma unroll
    for (int nf = 0; nf < 4; ++nf) {
        int e = tn * 128 + wn * 64 + nf * 16 + g * 4;
#pragma unroll
        for (int mf = 0; mf < 2; ++mf) {
            int m = tm * 64 + wm * 32 + mf * 16 + m16;
            int lr = m & (NL - 1);
            float4 xv = *(const float4*)(x + (size_t)m * NE + e);
            float4 pv = *(const float4*)(pos + (size_t)lr * NE + e);
            f32x4 v = acc[nf][mf];
            float4 o;
            o.x = v[0] + fast_tanh(xv.x + pv.x);
            o.y = v[1] + fast_tanh(xv.y + pv.y);
            o.z = v[2] + fast_tanh(xv.z + pv.z);
            o.w = v[3] + fast_tanh(xv.w + pv.w);
            *(float4*)(out + (size_t)m * NE + e) = o;
        }
    }
}

extern "C" void kernel_launch(void* const* d_in, const int* in_sizes, int n_in,
                              void* d_out, int out_size, void* d_ws, size_t ws_size,
                              hipStream_t stream) {
    const float* x   = (const float*)d_in[0];
    const float* pos = (const float*)d_in[1];
    const float* Wq  = (const float*)d_in[2];
    const float* Wk  = (const float*)d_in[3];
    const float* Wv  = (const float*)d_in[4];
    const float* Wo  = (const float*)d_in[5];
    float* out = (float*)d_out;

    char* ws = (char*)d_ws;
    _Float16* wqkv  = (_Float16*)(ws);              //    786,432 B
    _Float16* woh   = (_Float16*)(ws + 786432);     //    262,144 B
    _Float16* q_all = (_Float16*)(ws + 1048576);    // 16,777,216 B
    _Float16* k_all = (_Float16*)(ws + 17825792);   // 16,777,216 B
    _Float16* vT    = (_Float16*)(ws + 34603008);   // 16,777,216 B [c][token]
    _Float16* attn  = (_Float16*)(ws + 51380224);   // 16,777,216 B

    prep<<<dim3(2048), dim3(256), 0, stream>>>(Wq, Wk, Wv, Wo, wqkv, woh);
    proj_gemm<<<dim3(12 * 128), dim3(256), 0, stream>>>(wqkv, x, pos, q_all, k_all, vT);
    attn_kernel<<<dim3(1024), dim3(256), 0, stream>>>(q_all, k_all, vT, attn);
    final_gemm<<<dim3(512), dim3(256), 0, stream>>>(woh, attn, x, pos, out);
}

// Round 11
// 84.635 us; speedup vs baseline: 1.1845x; 1.1845x over previous
//
#include <hip/hip_runtime.h>
#include <cstdint>

#define NB 32
#define NL 512
#define NE 256
#define NH 8
#define ND 64
#define NM 16384   // NB*NL
#define NHD 512    // NH*ND

using half8  = __attribute__((ext_vector_type(8))) _Float16;
using half4  = __attribute__((ext_vector_type(4))) _Float16;
using f32x4  = __attribute__((ext_vector_type(4))) float;
using f32x16 = __attribute__((ext_vector_type(16))) float;
using u32x2  = __attribute__((ext_vector_type(2))) unsigned int;

__device__ __forceinline__ f32x4 mfma16(half8 a, half8 b, f32x4 c) {
    return __builtin_amdgcn_mfma_f32_16x16x32_f16(a, b, c, 0, 0, 0);
}
__device__ __forceinline__ f32x16 mfma32(half8 a, half8 b, f32x16 c) {
    return __builtin_amdgcn_mfma_f32_32x32x16_f16(a, b, c, 0, 0, 0);
}
// async global->LDS, 16B/lane; LDS dest = wave-uniform base + lane*16.
__device__ __forceinline__ void cp16_g2l(const void* g, void* l) {
    __builtin_amdgcn_global_load_lds(
        (const __attribute__((address_space(1))) void*)g,
        (__attribute__((address_space(3))) void*)l, 16, 0, 0);
}
// 2^x on the TRANS pipe (v_exp_f32), no libm dependence.
__device__ __forceinline__ float exp2fast(float x) {
    return __builtin_amdgcn_exp2f(x);
}
// fast tanh: ~6 ops, 2 on TRANS pipe. |err| ~1e-6, invisible under f16.
__device__ __forceinline__ float fast_tanh(float x) {
    float xc = fminf(fmaxf(x, -9.f), 9.f);
    float t = exp2fast(xc * 2.88539008178f);   // e^(2x) = 2^(2x*log2e)
    return (t - 1.f) * __builtin_amdgcn_rcpf(t + 1.f);
}
// pack two f32 -> two f16 in one u32 (v_cvt_pkrtz_f16_f32)
__device__ __forceinline__ uint32_t pk16(float a, float b) {
    auto h2 = __builtin_amdgcn_cvt_pkrtz(a, b);
    return __builtin_bit_cast(uint32_t, h2);
}

// ---------------- K0: fused weight repack + xph = f16(x+pos) ----------------
__global__ __launch_bounds__(256) void prep(
        const float* __restrict__ x, const float* __restrict__ pos,
        const float* __restrict__ Wq, const float* __restrict__ Wk,
        const float* __restrict__ Wv, const float* __restrict__ Wo,
        _Float16* __restrict__ wqkv, _Float16* __restrict__ woh,
        _Float16* __restrict__ xph) {
    int bid = blockIdx.x;
    if (bid < 2048) {
        int idx = bid * 256 + threadIdx.x;
        if (idx < 1536 * 256) {
            int n = idx >> 8, e = idx & 255;
            int s = n >> 9, h = (n >> 6) & 7, d = n & 63;
            const float* W = (s == 0) ? Wq : (s == 1) ? Wk : Wv;
            wqkv[idx] = (_Float16)W[(h * NE + e) * ND + d];
        } else {
            int j = idx - 1536 * 256;
            int e = j >> 9, f = j & 511;
            woh[j] = (_Float16)Wo[f * NE + e];
        }
    } else {
        int i = ((bid - 2048) * 256 + threadIdx.x) * 4;
        float4 xv = *(const float4*)(x + i);
        float4 pv = *(const float4*)(pos + (i & (NL * NE - 1)));
        half4 o;
        o[0] = (_Float16)(xv.x + pv.x);
        o[1] = (_Float16)(xv.y + pv.y);
        o[2] = (_Float16)(xv.z + pv.z);
        o[3] = (_Float16)(xv.w + pv.w);
        *(half4*)(xph + i) = o;
    }
}

// ---------------- K1: fused QKV projection GEMM ----------------
// Single-buffered 32 KB LDS (vs dbuf 64 KB): 4+ blocks/CU so inter-block TLP
// hides stage latency (m114: implicit overlap >= explicit dbuf here).
// BK=64, 128B LDS rows, XOR-swizzled via pre-swizzled global_load_lds source.
// q,k (tn<8): tanh -> [token][c]; v (tn>=8): operand-swap -> vT[c][token].
// Grid: XCD-chunked bijective remap (1536 = 8 x 12 x 16).
__global__ __launch_bounds__(256) void proj_gemm(
        const _Float16* __restrict__ wqkv, const _Float16* __restrict__ xph,
        _Float16* __restrict__ q_all, _Float16* __restrict__ k_all,
        _Float16* __restrict__ vT) {
    __shared__ _Float16 Alds[128 * 64];
    __shared__ _Float16 Blds[128 * 64];
    int tid = threadIdx.x;
    int w = tid >> 6, l = tid & 63;
    int bid = blockIdx.x;
    int xcd = bid & 7, local = bid >> 3;        // local in [0,192)
    int tn = local % 12;
    int tm = xcd * 16 + local / 12;             // contiguous tm chunk per XCD
    int wn = w >> 1, wm = w & 1;
    int m16 = l & 15, g = l >> 4;
    bool isv = (tn >= 8);
    int lrow8 = l >> 3;             // row within 8-row chunk
    int kc16 = (l & 7) ^ lrow8;     // pre-swizzled global 16B k-unit
    f32x4 acc[4][4] = {};

    const _Float16* Ag = wqkv + (size_t)tn * 128 * 256;
    const _Float16* Bg = xph + (size_t)tm * 128 * 256;

    for (int kt = 0; kt < 4; ++kt) {
#pragma unroll
        for (int i = 0; i < 4; ++i) {
            int cA = w * 4 + i;                 // 16 chunks of 1KB each
            int row = cA * 8 + lrow8;
            cp16_g2l(Ag + (size_t)row * 256 + kt * 64 + kc16 * 8,
                     Alds + cA * 512);
            cp16_g2l(Bg + (size_t)row * 256 + kt * 64 + kc16 * 8,
                     Blds + cA * 512);
        }
        __syncthreads();
#pragma unroll
        for (int ks = 0; ks < 2; ++ks) {
            half8 af[4], bf[4];
#pragma unroll
            for (int f = 0; f < 4; ++f) {
                int ra = wn * 64 + f * 16 + m16;
                int rb = wm * 64 + f * 16 + m16;
                af[f] = *(const half8*)(Alds + ra * 64 + (((ks * 4 + g) ^ (ra & 7)) << 3));
                bf[f] = *(const half8*)(Blds + rb * 64 + (((ks * 4 + g) ^ (rb & 7)) << 3));
            }
            if (!isv) {
#pragma unroll
                for (int nf = 0; nf < 4; ++nf)
#pragma unroll
                    for (int mf = 0; mf < 4; ++mf)
                        acc[nf][mf] = mfma16(af[nf], bf[mf], acc[nf][mf]);
            } else {
#pragma unroll
                for (int nf = 0; nf < 4; ++nf)
#pragma unroll
                    for (int mf = 0; mf < 4; ++mf)
                        acc[nf][mf] = mfma16(bf[mf], af[nf], acc[nf][mf]);
            }
        }
        __syncthreads();
    }
    if (!isv) {
        _Float16* dst = (tn < 4) ? q_all : k_all;
#pragma unroll
        for (int nf = 0; nf < 4; ++nf) {
            int c = (tn & 3) * 128 + wn * 64 + nf * 16 + g * 4;
#pragma unroll
            for (int mf = 0; mf < 4; ++mf) {
                int m = tm * 128 + wm * 64 + mf * 16 + m16;
                f32x4 v = acc[nf][mf];
                half4 hv;
#pragma unroll
                for (int r = 0; r < 4; ++r) hv[r] = (_Float16)fast_tanh(v[r]);
                *(half4*)(dst + (size_t)m * NHD + c) = hv;
            }
        }
    } else {
#pragma unroll
        for (int nf = 0; nf < 4; ++nf) {
            int c = (tn - 8) * 128 + wn * 64 + nf * 16 + m16;
#pragma unroll
            for (int mf = 0; mf < 4; ++mf) {
                int t0 = tm * 128 + wm * 64 + mf * 16 + g * 4;
                f32x4 v = acc[nf][mf];    // rows = tokens t0+r, col = c
                half4 hv;
#pragma unroll
                for (int r = 0; r < 4; ++r) hv[r] = (_Float16)fast_tanh(v[r]);
                *(half4*)(vT + (size_t)c * NM + t0) = hv;
            }
        }
    }
}

// ---------------- K2: flash attention, 32x32x16 MFMA ----------------
// (verified R9 structure, byte-identical)
__global__ __launch_bounds__(256, 3) void attn_kernel(
        const _Float16* __restrict__ q_all, const _Float16* __restrict__ k_all,
        const _Float16* __restrict__ vT, _Float16* __restrict__ attn_out) {
    __shared__ _Float16 Klds[2][64 * 64];   // [key][d], unit^=(key&7)
    __shared__ _Float16 Vtlds[2][64 * 64];  // [d][key], unit^=(d&7)
    int tid = threadIdx.x;
    int w = tid >> 6, l = tid & 63;
    int l31 = l & 31, hi = l >> 5;
    int bid = blockIdx.x;
    int qt = bid & 3, h = (bid >> 2) & 7, b = bid >> 5;
    const float C1 = 0.125f * 1.44269504089f;   // scale * log2(e)

    int qbase = qt * 128 + w * 32;
    half8 qf[4];   // B operand: [q=l31][d = ks*16 + hi*8]
    {
        const _Float16* qp = q_all + (size_t)(b * NL + qbase + l31) * NHD + h * ND + hi * 8;
#pragma unroll
        for (int ks = 0; ks < 4; ++ks) qf[ks] = *(const half8*)(qp + ks * 16);
    }

    f32x16 acc_o[2] = {};
    float mrow = -1e30f, lrow = 0.f;

    int st_row = tid >> 2;          // K: key / Vt: d
    int st_u0 = (tid & 3) * 2;      // two 16B units per thread
    const _Float16* kg = k_all + (size_t)(b * NL + st_row) * NHD + h * ND + st_u0 * 8;
    const _Float16* vg = vT + (size_t)(h * ND + st_row) * NM + b * NL + st_u0 * 8;
    int so0 = st_row * 64 + ((st_u0 ^ (st_row & 7)) << 3);
    int so1 = st_row * 64 + (((st_u0 + 1) ^ (st_row & 7)) << 3);

    uint4 kv0 = *(const uint4*)(kg);
    uint4 kv1 = *(const uint4*)(kg + 8);
    uint4 vv0 = *(const uint4*)(vg);
    uint4 vv1 = *(const uint4*)(vg + 8);
    *(uint4*)&Klds[0][so0] = kv0;   *(uint4*)&Klds[0][so1] = kv1;
    *(uint4*)&Vtlds[0][so0] = vv0;  *(uint4*)&Vtlds[0][so1] = vv1;
    __syncthreads();

    for (int kt = 0; kt < 8; ++kt) {
        int cur = kt & 1;
        if (kt < 7) {   // issue next-tile loads early (hide under compute)
            const _Float16* kp = kg + (size_t)(kt + 1) * 64 * NHD;
            const _Float16* vp = vg + (kt + 1) * 64;
            kv0 = *(const uint4*)(kp);      kv1 = *(const uint4*)(kp + 8);
            vv0 = *(const uint4*)(vp);      vv1 = *(const uint4*)(vp + 8);
        }
        // S^T = K Q^T : acc_s[kb2] rows=keys, cols=q
        f32x16 acc_s[2] = {};
        __builtin_amdgcn_s_setprio(1);
#pragma unroll
        for (int ks = 0; ks < 4; ++ks)
#pragma unroll
            for (int kb2 = 0; kb2 < 2; ++kb2) {
                int key = kb2 * 32 + l31;
                half8 kb = *(const half8*)(&Klds[cur][key * 64 + (((ks * 2 + hi) ^ (key & 7)) << 3)]);
                acc_s[kb2] = mfma32(kb, qf[ks], acc_s[kb2]);
            }
        __builtin_amdgcn_s_setprio(0);
        // online softmax, q = l31 per lane
        float mx = -1e30f;
#pragma unroll
        for (int kb2 = 0; kb2 < 2; ++kb2)
#pragma unroll
            for (int j = 0; j < 16; ++j) mx = fmaxf(mx, acc_s[kb2][j]);
        mx = fmaxf(mx, __shfl_xor(mx, 32));
        mx *= 0.125f;
        if (!__all(mx <= mrow + 8.f)) {   // defer-max: rescale rarely fires
            float mn = fmaxf(mrow, mx);
            float alpha = exp2fast((mrow - mn) * 1.44269504089f);
            mrow = mn;
            lrow *= alpha;
            float aq[16];
#pragma unroll
            for (int c = 0; c < 4; ++c)
#pragma unroll
                for (int r = 0; r < 4; ++r)
                    aq[c * 4 + r] = __shfl(alpha, c * 8 + hi * 4 + r);
#pragma unroll
            for (int d2 = 0; d2 < 2; ++d2)
#pragma unroll
                for (int j = 0; j < 16; ++j) acc_o[d2][j] *= aq[j];
        }
        // p = exp2(fma(s, C1, -ml)); pack pairs to f16 words in regs
        float ml = mrow * 1.44269504089f;
        float rs = 0.f;
        uint32_t cw[2][4][2];
#pragma unroll
        for (int kb2 = 0; kb2 < 2; ++kb2)
#pragma unroll
            for (int a = 0; a < 4; ++a)
#pragma unroll
                for (int p = 0; p < 2; ++p) {
                    float p0 = exp2fast(fmaf(acc_s[kb2][4 * a + 2 * p],     C1, -ml));
                    float p1 = exp2fast(fmaf(acc_s[kb2][4 * a + 2 * p + 1], C1, -ml));
                    rs += p0 + p1;
                    cw[kb2][a][p] = pk16(p0, p1);
                }
        rs += __shfl_xor(rs, 32);
        lrow += rs;
        // O += P V   (pa assembled in-register via permlane32_swap)
        __builtin_amdgcn_s_setprio(1);
#pragma unroll
        for (int ks = 0; ks < 4; ++ks) {
            int kb2 = ks >> 1, s = ks & 1;
            u32x2 r0 = __builtin_amdgcn_permlane32_swap(
                cw[kb2][2 * s][0], cw[kb2][2 * s + 1][0], false, false);
            u32x2 r1 = __builtin_amdgcn_permlane32_swap(
                cw[kb2][2 * s][1], cw[kb2][2 * s + 1][1], false, false);
            union { uint32_t u[4]; half8 h; } pu;
            pu.u[0] = r0[0];  pu.u[1] = r1[0];   // e=0..3 (hi'=0 owner)
            pu.u[2] = r0[1];  pu.u[3] = r1[1];   // e=4..7 (hi'=1 owner)
#pragma unroll
            for (int d2 = 0; d2 < 2; ++d2) {
                int d = d2 * 32 + l31;
                half8 vb = *(const half8*)(&Vtlds[cur][d * 64 + (((ks * 2 + hi) ^ (d & 7)) << 3)]);
                acc_o[d2] = mfma32(pu.h, vb, acc_o[d2]);
            }
        }
        __builtin_amdgcn_s_setprio(0);
        if (kt < 7) {   // write prefetched tile, single barrier per tile
            int nxt = cur ^ 1;
            *(uint4*)&Klds[nxt][so0] = kv0;   *(uint4*)&Klds[nxt][so1] = kv1;
            *(uint4*)&Vtlds[nxt][so0] = vv0;  *(uint4*)&Vtlds[nxt][so1] = vv1;
            __syncthreads();
        }
    }
    // epilogue: O[q][d], rows q from reg mapping, col d = d2*32 + l31
    size_t orow0 = (size_t)(b * NL + qbase);
#pragma unroll
    for (int c = 0; c < 4; ++c)
#pragma unroll
        for (int r = 0; r < 4; ++r) {
            int qrow = c * 8 + hi * 4 + r;
            float inv = 1.f / __shfl(lrow, qrow);
#pragma unroll
            for (int d2 = 0; d2 < 2; ++d2)
                attn_out[(orow0 + qrow) * NHD + h * ND + d2 * 32 + l31] =
                    (_Float16)(acc_o[d2][c * 4 + r] * inv);
        }
}

// ---------------- K3: output projection + f16 tanh residual ----------------
// tile 128e x 64m -> 512 blocks. BK=64, swizzled dbuf LDS, 2-phase pipeline.
// Residual from xph (f16 x+pos).
__global__ __launch_bounds__(256) void final_gemm(
        const _Float16* __restrict__ woh, const _Float16* __restrict__ attn,
        const _Float16* __restrict__ xph, float* __restrict__ out) {
    __shared__ _Float16 Alds[2][128 * 64];
    __shared__ _Float16 Blds[2][64 * 64];
    int tid = threadIdx.x;
    int w = tid >> 6, l = tid & 63;
    int tn = blockIdx.x & 1, tm = blockIdx.x >> 1;
    int wn = w >> 1, wm = w & 1;
    int m16 = l & 15, g = l >> 4;
    int lrow8 = l >> 3;
    int kc16 = (l & 7) ^ lrow8;
    f32x4 acc[4][2] = {};

    const _Float16* Ag = woh + (size_t)tn * 128 * 512;
    const _Float16* Bg = attn + (size_t)tm * 64 * 512;

#define FIN_STAGE(kt, buf)                                                    \
    _Pragma("unroll") for (int i = 0; i < 4; ++i) {                           \
        int cA = w * 4 + i;                                                   \
        int row = cA * 8 + lrow8;                                             \
        cp16_g2l(Ag + (size_t)row * 512 + (kt) * 64 + kc16 * 8,               \
                 &Alds[buf][cA * 512]);                                       \
    }                                                                         \
    _Pragma("unroll") for (int i = 0; i < 2; ++i) {                           \
        int cB = w * 2 + i;                                                   \
        int row = cB * 8 + lrow8;                                             \
        cp16_g2l(Bg + (size_t)row * 512 + (kt) * 64 + kc16 * 8,               \
                 &Blds[buf][cB * 512]);                                       \
    }

    FIN_STAGE(0, 0);
    __syncthreads();
    int cur = 0;
    for (int kt = 0; kt < 8; ++kt) {
        if (kt < 7) { FIN_STAGE(kt + 1, cur ^ 1); }
#pragma unroll
        for (int ks = 0; ks < 2; ++ks) {
            half8 af[4], bf[2];
#pragma unroll
            for (int f = 0; f < 4; ++f) {
                int ra = wn * 64 + f * 16 + m16;
                af[f] = *(const half8*)(&Alds[cur][ra * 64 + (((ks * 4 + g) ^ (ra & 7)) << 3)]);
            }
#pragma unroll
            for (int f = 0; f < 2; ++f) {
                int rb = wm * 32 + f * 16 + m16;
                bf[f] = *(const half8*)(&Blds[cur][rb * 64 + (((ks * 4 + g) ^ (rb & 7)) << 3)]);
            }
#pragma unroll
            for (int nf = 0; nf < 4; ++nf)
#pragma unroll
                for (int mf = 0; mf < 2; ++mf)
                    acc[nf][mf] = mfma16(af[nf], bf[mf], acc[nf][mf]);
        }
        __syncthreads();
        cur ^= 1;
    }
#undef FIN_STAGE
#pragma unroll
    for (int nf = 0; nf < 4; ++nf) {
        int e = tn * 128 + wn * 64 + nf * 16 + g * 4;
#pragma unroll
        for (int mf = 0; mf < 2; ++mf) {
            int m = tm * 64 + wm * 32 + mf * 16 + m16;
            half4 hx = *(const half4*)(xph + (size_t)m * NE + e);
            f32x4 v = acc[nf][mf];
            float4 o;
            o.x = v[0] + fast_tanh((float)hx[0]);
            o.y = v[1] + fast_tanh((float)hx[1]);
            o.z = v[2] + fast_tanh((float)hx[2]);
            o.w = v[3] + fast_tanh((float)hx[3]);
            *(float4*)(out + (size_t)m * NE + e) = o;
        }
    }
}

extern "C" void kernel_launch(void* const* d_in, const int* in_sizes, int n_in,
                              void* d_out, int out_size, void* d_ws, size_t ws_size,
                              hipStream_t stream) {
    const float* x   = (const float*)d_in[0];
    const float* pos = (const float*)d_in[1];
    const float* Wq  = (const float*)d_in[2];
    const float* Wk  = (const float*)d_in[3];
    const float* Wv  = (const float*)d_in[4];
    const float* Wo  = (const float*)d_in[5];
    float* out = (float*)d_out;

    char* ws = (char*)d_ws;
    _Float16* xph   = (_Float16*)(ws);              //  8,388,608 B
    _Float16* wqkv  = (_Float16*)(ws + 8388608);    //    786,432 B
    _Float16* woh   = (_Float16*)(ws + 9175040);    //    262,144 B
    _Float16* q_all = (_Float16*)(ws + 9437184);    // 16,777,216 B
    _Float16* k_all = (_Float16*)(ws + 26214400);   // 16,777,216 B
    _Float16* vT    = (_Float16*)(ws + 42991616);   // 16,777,216 B [c][token]
    _Float16* attn  = (_Float16*)(ws + 59768832);   // 16,777,216 B

    prep<<<dim3(6144), dim3(256), 0, stream>>>(x, pos, Wq, Wk, Wv, Wo, wqkv, woh, xph);
    proj_gemm<<<dim3(12 * 128), dim3(256), 0, stream>>>(wqkv, xph, q_all, k_all, vT);
    attn_kernel<<<dim3(1024), dim3(256), 0, stream>>>(q_all, k_all, vT, attn);
    final_gemm<<<dim3(512), dim3(256), 0, stream>>>(woh, attn, xph, out);
}

// Round 12
// 78.516 us; speedup vs baseline: 1.2768x; 1.0779x over previous
//
#include <hip/hip_runtime.h>
#include <cstdint>

#define NB 32
#define NL 512
#define NE 256
#define NH 8
#define ND 64
#define NM 16384   // NB*NL
#define NHD 512    // NH*ND

using half8  = __attribute__((ext_vector_type(8))) _Float16;
using half4  = __attribute__((ext_vector_type(4))) _Float16;
using f32x4  = __attribute__((ext_vector_type(4))) float;
using f32x16 = __attribute__((ext_vector_type(16))) float;
using u32x2  = __attribute__((ext_vector_type(2))) unsigned int;

__device__ __forceinline__ f32x4 mfma16(half8 a, half8 b, f32x4 c) {
    return __builtin_amdgcn_mfma_f32_16x16x32_f16(a, b, c, 0, 0, 0);
}
__device__ __forceinline__ f32x16 mfma32(half8 a, half8 b, f32x16 c) {
    return __builtin_amdgcn_mfma_f32_32x32x16_f16(a, b, c, 0, 0, 0);
}
// async global->LDS, 16B/lane; LDS dest = wave-uniform base + lane*16.
__device__ __forceinline__ void cp16_g2l(const void* g, void* l) {
    __builtin_amdgcn_global_load_lds(
        (const __attribute__((address_space(1))) void*)g,
        (__attribute__((address_space(3))) void*)l, 16, 0, 0);
}
// 2^x on the TRANS pipe (v_exp_f32), no libm dependence.
__device__ __forceinline__ float exp2fast(float x) {
    return __builtin_amdgcn_exp2f(x);
}
// fast tanh: ~6 ops, 2 on TRANS pipe. |err| ~1e-6, invisible under f16.
__device__ __forceinline__ float fast_tanh(float x) {
    float xc = fminf(fmaxf(x, -9.f), 9.f);
    float t = exp2fast(xc * 2.88539008178f);   // e^(2x) = 2^(2x*log2e)
    return (t - 1.f) * __builtin_amdgcn_rcpf(t + 1.f);
}
// pack two f32 -> two f16 in one u32 (v_cvt_pkrtz_f16_f32)
__device__ __forceinline__ uint32_t pk16(float a, float b) {
    auto h2 = __builtin_amdgcn_cvt_pkrtz(a, b);
    return __builtin_bit_cast(uint32_t, h2);
}

// ---------------- K0: fused weight repack + xph = f16(x+pos) ----------------
__global__ __launch_bounds__(256) void prep(
        const float* __restrict__ x, const float* __restrict__ pos,
        const float* __restrict__ Wq, const float* __restrict__ Wk,
        const float* __restrict__ Wv, const float* __restrict__ Wo,
        _Float16* __restrict__ wqkv, _Float16* __restrict__ woh,
        _Float16* __restrict__ xph) {
    int bid = blockIdx.x;
    if (bid < 2048) {
        int idx = bid * 256 + threadIdx.x;
        if (idx < 1536 * 256) {
            int n = idx >> 8, e = idx & 255;
            int s = n >> 9, h = (n >> 6) & 7, d = n & 63;
            const float* W = (s == 0) ? Wq : (s == 1) ? Wk : Wv;
            wqkv[idx] = (_Float16)W[(h * NE + e) * ND + d];
        } else {
            int j = idx - 1536 * 256;
            int e = j >> 9, f = j & 511;
            woh[j] = (_Float16)Wo[f * NE + e];
        }
    } else {
        int i = ((bid - 2048) * 256 + threadIdx.x) * 4;
        float4 xv = *(const float4*)(x + i);
        float4 pv = *(const float4*)(pos + (i & (NL * NE - 1)));
        half4 o;
        o[0] = (_Float16)(xv.x + pv.x);
        o[1] = (_Float16)(xv.y + pv.y);
        o[2] = (_Float16)(xv.z + pv.z);
        o[3] = (_Float16)(xv.w + pv.w);
        *(half4*)(xph + i) = o;
    }
}

// ---------------- K1: K/V projection GEMM (Q moved into attn) ----------------
// Single-buffered 32 KB LDS; BK=64; XOR-swizzled (pre-swizzled gload src).
// k blocks (tn<4): tanh -> k_all[token][c]; v (tn>=4): swap -> vT[c][token].
// Grid: 1024 = 8 XCD x (8 tn x 16 tm), tm contiguous per XCD.
__global__ __launch_bounds__(256) void proj_gemm(
        const _Float16* __restrict__ wqkv, const _Float16* __restrict__ xph,
        _Float16* __restrict__ k_all, _Float16* __restrict__ vT) {
    __shared__ _Float16 Alds[128 * 64];
    __shared__ _Float16 Blds[128 * 64];
    int tid = threadIdx.x;
    int w = tid >> 6, l = tid & 63;
    int bid = blockIdx.x;
    int xcd = bid & 7, local = bid >> 3;        // local in [0,128)
    int tn = local & 7;
    int tm = xcd * 16 + (local >> 3);           // contiguous tm chunk per XCD
    int wn = w >> 1, wm = w & 1;
    int m16 = l & 15, g = l >> 4;
    bool isv = (tn >= 4);
    int lrow8 = l >> 3;             // row within 8-row chunk
    int kc16 = (l & 7) ^ lrow8;     // pre-swizzled global 16B k-unit
    f32x4 acc[4][4] = {};

    const _Float16* Ag = wqkv + (size_t)(512 + tn * 128) * 256;  // k/v rows
    const _Float16* Bg = xph + (size_t)tm * 128 * 256;

    for (int kt = 0; kt < 4; ++kt) {
#pragma unroll
        for (int i = 0; i < 4; ++i) {
            int cA = w * 4 + i;                 // 16 chunks of 1KB each
            int row = cA * 8 + lrow8;
            cp16_g2l(Ag + (size_t)row * 256 + kt * 64 + kc16 * 8,
                     Alds + cA * 512);
            cp16_g2l(Bg + (size_t)row * 256 + kt * 64 + kc16 * 8,
                     Blds + cA * 512);
        }
        __syncthreads();
#pragma unroll
        for (int ks = 0; ks < 2; ++ks) {
            half8 af[4], bf[4];
#pragma unroll
            for (int f = 0; f < 4; ++f) {
                int ra = wn * 64 + f * 16 + m16;
                int rb = wm * 64 + f * 16 + m16;
                af[f] = *(const half8*)(Alds + ra * 64 + (((ks * 4 + g) ^ (ra & 7)) << 3));
                bf[f] = *(const half8*)(Blds + rb * 64 + (((ks * 4 + g) ^ (rb & 7)) << 3));
            }
            if (!isv) {
#pragma unroll
                for (int nf = 0; nf < 4; ++nf)
#pragma unroll
                    for (int mf = 0; mf < 4; ++mf)
                        acc[nf][mf] = mfma16(af[nf], bf[mf], acc[nf][mf]);
            } else {
#pragma unroll
                for (int nf = 0; nf < 4; ++nf)
#pragma unroll
                    for (int mf = 0; mf < 4; ++mf)
                        acc[nf][mf] = mfma16(bf[mf], af[nf], acc[nf][mf]);
            }
        }
        __syncthreads();
    }
    if (!isv) {
#pragma unroll
        for (int nf = 0; nf < 4; ++nf) {
            int c = tn * 128 + wn * 64 + nf * 16 + g * 4;
#pragma unroll
            for (int mf = 0; mf < 4; ++mf) {
                int m = tm * 128 + wm * 64 + mf * 16 + m16;
                f32x4 v = acc[nf][mf];
                half4 hv;
#pragma unroll
                for (int r = 0; r < 4; ++r) hv[r] = (_Float16)fast_tanh(v[r]);
                *(half4*)(k_all + (size_t)m * NHD + c) = hv;
            }
        }
    } else {
#pragma unroll
        for (int nf = 0; nf < 4; ++nf) {
            int c = (tn - 4) * 128 + wn * 64 + nf * 16 + m16;
#pragma unroll
            for (int mf = 0; mf < 4; ++mf) {
                int t0 = tm * 128 + wm * 64 + mf * 16 + g * 4;
                f32x4 v = acc[nf][mf];    // rows = tokens t0+r, col = c
                half4 hv;
#pragma unroll
                for (int r = 0; r < 4; ++r) hv[r] = (_Float16)fast_tanh(v[r]);
                *(half4*)(vT + (size_t)c * NM + t0) = hv;
            }
        }
    }
}

// ---------------- K2: flash attention w/ fused Q projection ----------------
// Q = tanh(xph_tile @ Wq[h]) computed in-block (XQ/WQ staged in the K/V LDS),
// reassembled into qf[4] via the T12 cvt_pk + permlane32_swap wiring (same
// verified derivation as P: owned d = 8a+4hi+b -> needed d = ks*16+hi*8+j).
// Grid: 1024 = 8 XCD x 128, h fastest -> K/V + xq panels are XCD-local.
__global__ __launch_bounds__(256, 3) void attn_kernel(
        const _Float16* __restrict__ wqkv, const _Float16* __restrict__ xph,
        const _Float16* __restrict__ k_all, const _Float16* __restrict__ vT,
        _Float16* __restrict__ attn_out) {
    __shared__ _Float16 Klds[2][64 * 64];   // [key][d], unit^=(key&7)
    __shared__ _Float16 Vtlds[2][64 * 64];  // [d][key], unit^=(d&7)
    int tid = threadIdx.x;
    int w = tid >> 6, l = tid & 63;
    int l31 = l & 31, hi = l >> 5;
    int g0 = (blockIdx.x & 7) * 128 + (blockIdx.x >> 3);  // XCD-chunked id
    int h = g0 & 7, bq = g0 >> 3;
    int b = bq >> 2, qt = bq & 3;
    const float C1 = 0.125f * 1.44269504089f;   // scale * log2(e)

    int qbase = qt * 128 + w * 32;

    // --- Q projection phase (uses K/V LDS as scratch) ---
    _Float16* XQ = &Klds[0][0];     // 16 KB: [128 q][64 k]
    _Float16* WQ = &Vtlds[0][0];    // 8 KB:  [64 d][64 k]
    f32x16 acc_q[2] = {};
    {
        const _Float16* xg = xph + (size_t)(b * NL + qt * 128) * 256;
        const _Float16* wg = wqkv + (size_t)(h * 64) * 256;   // q rows: h*64+d
        int lrow8 = l >> 3;
        int kc16 = (l & 7) ^ lrow8;
        for (int kt = 0; kt < 4; ++kt) {
#pragma unroll
            for (int i = 0; i < 4; ++i) {
                int c = w * 4 + i;
                int row = c * 8 + lrow8;
                cp16_g2l(xg + (size_t)row * 256 + kt * 64 + kc16 * 8, XQ + c * 512);
            }
#pragma unroll
            for (int i = 0; i < 2; ++i) {
                int c = w * 2 + i;
                int row = c * 8 + lrow8;
                cp16_g2l(wg + (size_t)row * 256 + kt * 64 + kc16 * 8, WQ + c * 512);
            }
            __syncthreads();
#pragma unroll
            for (int kp = 0; kp < 4; ++kp) {
                int u = kp * 2 + hi;
                int rq = w * 32 + l31;
                half8 xf = *(const half8*)(XQ + rq * 64 + ((u ^ (rq & 7)) << 3));
#pragma unroll
                for (int d2 = 0; d2 < 2; ++d2) {
                    int rd = d2 * 32 + l31;
                    half8 wf = *(const half8*)(WQ + rd * 64 + ((u ^ (rd & 7)) << 3));
                    acc_q[d2] = mfma32(wf, xf, acc_q[d2]);   // rows=d, cols=q
                }
            }
            __syncthreads();
        }
    }
    half8 qf[4];   // [q=l31][d = ks*16 + hi*8 + j]
    {
        uint32_t qw[2][4][2];
#pragma unroll
        for (int d2 = 0; d2 < 2; ++d2)
#pragma unroll
            for (int a = 0; a < 4; ++a)
#pragma unroll
                for (int p = 0; p < 2; ++p)
                    qw[d2][a][p] = pk16(fast_tanh(acc_q[d2][4 * a + 2 * p]),
                                        fast_tanh(acc_q[d2][4 * a + 2 * p + 1]));
#pragma unroll
        for (int ks = 0; ks < 4; ++ks) {
            int d2 = ks >> 1, s = ks & 1;
            u32x2 r0 = __builtin_amdgcn_permlane32_swap(
                qw[d2][2 * s][0], qw[d2][2 * s + 1][0], false, false);
            u32x2 r1 = __builtin_amdgcn_permlane32_swap(
                qw[d2][2 * s][1], qw[d2][2 * s + 1][1], false, false);
            union { uint32_t u[4]; half8 h; } pu;
            pu.u[0] = r0[0];  pu.u[1] = r1[0];
            pu.u[2] = r0[1];  pu.u[3] = r1[1];
            qf[ks] = pu.h;
        }
    }

    f32x16 acc_o[2] = {};
    float mrow = -1e30f, lrow = 0.f;

    int st_row = tid >> 2;          // K: key / Vt: d
    int st_u0 = (tid & 3) * 2;      // two 16B units per thread
    const _Float16* kg = k_all + (size_t)(b * NL + st_row) * NHD + h * ND + st_u0 * 8;
    const _Float16* vg = vT + (size_t)(h * ND + st_row) * NM + b * NL + st_u0 * 8;
    int so0 = st_row * 64 + ((st_u0 ^ (st_row & 7)) << 3);
    int so1 = st_row * 64 + (((st_u0 + 1) ^ (st_row & 7)) << 3);

    uint4 kv0 = *(const uint4*)(kg);
    uint4 kv1 = *(const uint4*)(kg + 8);
    uint4 vv0 = *(const uint4*)(vg);
    uint4 vv1 = *(const uint4*)(vg + 8);
    *(uint4*)&Klds[0][so0] = kv0;   *(uint4*)&Klds[0][so1] = kv1;
    *(uint4*)&Vtlds[0][so0] = vv0;  *(uint4*)&Vtlds[0][so1] = vv1;
    __syncthreads();

    for (int kt = 0; kt < 8; ++kt) {
        int cur = kt & 1;
        if (kt < 7) {   // issue next-tile loads early (hide under compute)
            const _Float16* kp = kg + (size_t)(kt + 1) * 64 * NHD;
            const _Float16* vp = vg + (kt + 1) * 64;
            kv0 = *(const uint4*)(kp);      kv1 = *(const uint4*)(kp + 8);
            vv0 = *(const uint4*)(vp);      vv1 = *(const uint4*)(vp + 8);
        }
        // S^T = K Q^T : acc_s[kb2] rows=keys, cols=q
        f32x16 acc_s[2] = {};
        __builtin_amdgcn_s_setprio(1);
#pragma unroll
        for (int ks = 0; ks < 4; ++ks)
#pragma unroll
            for (int kb2 = 0; kb2 < 2; ++kb2) {
                int key = kb2 * 32 + l31;
                half8 kb = *(const half8*)(&Klds[cur][key * 64 + (((ks * 2 + hi) ^ (key & 7)) << 3)]);
                acc_s[kb2] = mfma32(kb, qf[ks], acc_s[kb2]);
            }
        __builtin_amdgcn_s_setprio(0);
        // online softmax, q = l31 per lane
        float mx = -1e30f;
#pragma unroll
        for (int kb2 = 0; kb2 < 2; ++kb2)
#pragma unroll
            for (int j = 0; j < 16; ++j) mx = fmaxf(mx, acc_s[kb2][j]);
        mx = fmaxf(mx, __shfl_xor(mx, 32));
        mx *= 0.125f;
        if (!__all(mx <= mrow + 8.f)) {   // defer-max: rescale rarely fires
            float mn = fmaxf(mrow, mx);
            float alpha = exp2fast((mrow - mn) * 1.44269504089f);
            mrow = mn;
            lrow *= alpha;
            float aq[16];
#pragma unroll
            for (int c = 0; c < 4; ++c)
#pragma unroll
                for (int r = 0; r < 4; ++r)
                    aq[c * 4 + r] = __shfl(alpha, c * 8 + hi * 4 + r);
#pragma unroll
            for (int d2 = 0; d2 < 2; ++d2)
#pragma unroll
                for (int j = 0; j < 16; ++j) acc_o[d2][j] *= aq[j];
        }
        // p = exp2(fma(s, C1, -ml)); pack pairs to f16 words in regs
        float ml = mrow * 1.44269504089f;
        float rs = 0.f;
        uint32_t cw[2][4][2];
#pragma unroll
        for (int kb2 = 0; kb2 < 2; ++kb2)
#pragma unroll
            for (int a = 0; a < 4; ++a)
#pragma unroll
                for (int p = 0; p < 2; ++p) {
                    float p0 = exp2fast(fmaf(acc_s[kb2][4 * a + 2 * p],     C1, -ml));
                    float p1 = exp2fast(fmaf(acc_s[kb2][4 * a + 2 * p + 1], C1, -ml));
                    rs += p0 + p1;
                    cw[kb2][a][p] = pk16(p0, p1);
                }
        rs += __shfl_xor(rs, 32);
        lrow += rs;
        // O += P V   (pa assembled in-register via permlane32_swap)
        __builtin_amdgcn_s_setprio(1);
#pragma unroll
        for (int ks = 0; ks < 4; ++ks) {
            int kb2 = ks >> 1, s = ks & 1;
            u32x2 r0 = __builtin_amdgcn_permlane32_swap(
                cw[kb2][2 * s][0], cw[kb2][2 * s + 1][0], false, false);
            u32x2 r1 = __builtin_amdgcn_permlane32_swap(
                cw[kb2][2 * s][1], cw[kb2][2 * s + 1][1], false, false);
            union { uint32_t u[4]; half8 h; } pu;
            pu.u[0] = r0[0];  pu.u[1] = r1[0];   // e=0..3 (hi'=0 owner)
            pu.u[2] = r0[1];  pu.u[3] = r1[1];   // e=4..7 (hi'=1 owner)
#pragma unroll
            for (int d2 = 0; d2 < 2; ++d2) {
                int d = d2 * 32 + l31;
                half8 vb = *(const half8*)(&Vtlds[cur][d * 64 + (((ks * 2 + hi) ^ (d & 7)) << 3)]);
                acc_o[d2] = mfma32(pu.h, vb, acc_o[d2]);
            }
        }
        __builtin_amdgcn_s_setprio(0);
        if (kt < 7) {   // write prefetched tile, single barrier per tile
            int nxt = cur ^ 1;
            *(uint4*)&Klds[nxt][so0] = kv0;   *(uint4*)&Klds[nxt][so1] = kv1;
            *(uint4*)&Vtlds[nxt][so0] = vv0;  *(uint4*)&Vtlds[nxt][so1] = vv1;
            __syncthreads();
        }
    }
    // epilogue: O[q][d], rows q from reg mapping, col d = d2*32 + l31
    size_t orow0 = (size_t)(b * NL + qbase);
#pragma unroll
    for (int c = 0; c < 4; ++c)
#pragma unroll
        for (int r = 0; r < 4; ++r) {
            int qrow = c * 8 + hi * 4 + r;
            float inv = 1.f / __shfl(lrow, qrow);
#pragma unroll
            for (int d2 = 0; d2 < 2; ++d2)
                attn_out[(orow0 + qrow) * NHD + h * ND + d2 * 32 + l31] =
                    (_Float16)(acc_o[d2][c * 4 + r] * inv);
        }
}

// ---------------- K3: output projection + f16 tanh residual ----------------
// tile 128e x 64m. BK=64, swizzled dbuf LDS, 2-phase pipeline.
// Grid: 512 = 8 XCD x (2 tn x 32 tm) -> attn B-panel fetched once per XCD.
__global__ __launch_bounds__(256) void final_gemm(
        const _Float16* __restrict__ woh, const _Float16* __restrict__ attn,
        const _Float16* __restrict__ xph, float* __restrict__ out) {
    __shared__ _Float16 Alds[2][128 * 64];
    __shared__ _Float16 Blds[2][64 * 64];
    int tid = threadIdx.x;
    int w = tid >> 6, l = tid & 63;
    int bid = blockIdx.x;
    int xcd = bid & 7, local = bid >> 3;   // 0..63
    int tn = local & 1;
    int tm = xcd * 32 + (local >> 1);
    int wn = w >> 1, wm = w & 1;
    int m16 = l & 15, g = l >> 4;
    int lrow8 = l >> 3;
    int kc16 = (l & 7) ^ lrow8;
    f32x4 acc[4][2] = {};

    const _Float16* Ag = woh + (size_t)tn * 128 * 512;
    const _Float16* Bg = attn + (size_t)tm * 64 * 512;

#define FIN_STAGE(kt, buf)                                                    \
    _Pragma("unroll") for (int i = 0; i < 4; ++i) {                           \
        int cA = w * 4 + i;                                                   \
        int row = cA * 8 + lrow8;                                             \
        cp16_g2l(Ag + (size_t)row * 512 + (kt) * 64 + kc16 * 8,               \
                 &Alds[buf][cA * 512]);                                       \
    }                                                                         \
    _Pragma("unroll") for (int i = 0; i < 2; ++i) {                           \
        int cB = w * 2 + i;                                                   \
        int row = cB * 8 + lrow8;                                             \
        cp16_g2l(Bg + (size_t)row * 512 + (kt) * 64 + kc16 * 8,               \
                 &Blds[buf][cB * 512]);                                       \
    }

    FIN_STAGE(0, 0);
    __syncthreads();
    int cur = 0;
    for (int kt = 0; kt < 8; ++kt) {
        if (kt < 7) { FIN_STAGE(kt + 1, cur ^ 1); }
#pragma unroll
        for (int ks = 0; ks < 2; ++ks) {
            half8 af[4], bf[2];
#pragma unroll
            for (int f = 0; f < 4; ++f) {
                int ra = wn * 64 + f * 16 + m16;
                af[f] = *(const half8*)(&Alds[cur][ra * 64 + (((ks * 4 + g) ^ (ra & 7)) << 3)]);
            }
#pragma unroll
            for (int f = 0; f < 2; ++f) {
                int rb = wm * 32 + f * 16 + m16;
                bf[f] = *(const half8*)(&Blds[cur][rb * 64 + (((ks * 4 + g) ^ (rb & 7)) << 3)]);
            }
#pragma unroll
            for (int nf = 0; nf < 4; ++nf)
#pragma unroll
                for (int mf = 0; mf < 2; ++mf)
                    acc[nf][mf] = mfma16(af[nf], bf[mf], acc[nf][mf]);
        }
        __syncthreads();
        cur ^= 1;
    }
#undef FIN_STAGE
#pragma unroll
    for (int nf = 0; nf < 4; ++nf) {
        int e = tn * 128 + wn * 64 + nf * 16 + g * 4;
#pragma unroll
        for (int mf = 0; mf < 2; ++mf) {
            int m = tm * 64 + wm * 32 + mf * 16 + m16;
            half4 hx = *(const half4*)(xph + (size_t)m * NE + e);
            f32x4 v = acc[nf][mf];
            float4 o;
            o.x = v[0] + fast_tanh((float)hx[0]);
            o.y = v[1] + fast_tanh((float)hx[1]);
            o.z = v[2] + fast_tanh((float)hx[2]);
            o.w = v[3] + fast_tanh((float)hx[3]);
            *(float4*)(out + (size_t)m * NE + e) = o;
        }
    }
}

extern "C" void kernel_launch(void* const* d_in, const int* in_sizes, int n_in,
                              void* d_out, int out_size, void* d_ws, size_t ws_size,
                              hipStream_t stream) {
    const float* x   = (const float*)d_in[0];
    const float* pos = (const float*)d_in[1];
    const float* Wq  = (const float*)d_in[2];
    const float* Wk  = (const float*)d_in[3];
    const float* Wv  = (const float*)d_in[4];
    const float* Wo  = (const float*)d_in[5];
    float* out = (float*)d_out;

    char* ws = (char*)d_ws;
    _Float16* xph   = (_Float16*)(ws);              //  8,388,608 B
    _Float16* wqkv  = (_Float16*)(ws + 8388608);    //    786,432 B
    _Float16* woh   = (_Float16*)(ws + 9175040);    //    262,144 B
    _Float16* k_all = (_Float16*)(ws + 9437184);    // 16,777,216 B
    _Float16* vT    = (_Float16*)(ws + 26214400);   // 16,777,216 B [c][token]
    _Float16* attn  = (_Float16*)(ws + 42991616);   // 16,777,216 B

    prep<<<dim3(6144), dim3(256), 0, stream>>>(x, pos, Wq, Wk, Wv, Wo, wqkv, woh, xph);
    proj_gemm<<<dim3(1024), dim3(256), 0, stream>>>(wqkv, xph, k_all, vT);
    attn_kernel<<<dim3(1024), dim3(256), 0, stream>>>(wqkv, xph, k_all, vT, attn);
    final_gemm<<<dim3(512), dim3(256), 0, stream>>>(woh, attn, xph, out);
}

// Round 14
// 74.332 us; speedup vs baseline: 1.3487x; 1.0563x over previous
//
#include <hip/hip_runtime.h>
#include <cstdint>

#define NB 32
#define NL 512
#define NE 256
#define NH 8
#define ND 64
#define NM 16384   // NB*NL
#define NHD 512    // NH*ND

using half8  = __attribute__((ext_vector_type(8))) _Float16;
using half4  = __attribute__((ext_vector_type(4))) _Float16;
using f32x4  = __attribute__((ext_vector_type(4))) float;
using f32x16 = __attribute__((ext_vector_type(16))) float;
using u32x2  = __attribute__((ext_vector_type(2))) unsigned int;

__device__ __forceinline__ f32x4 mfma16(half8 a, half8 b, f32x4 c) {
    return __builtin_amdgcn_mfma_f32_16x16x32_f16(a, b, c, 0, 0, 0);
}
__device__ __forceinline__ f32x16 mfma32(half8 a, half8 b, f32x16 c) {
    return __builtin_amdgcn_mfma_f32_32x32x16_f16(a, b, c, 0, 0, 0);
}
// async global->LDS, 16B/lane; LDS dest = wave-uniform base + lane*16.
__device__ __forceinline__ void cp16_g2l(const void* g, void* l) {
    __builtin_amdgcn_global_load_lds(
        (const __attribute__((address_space(1))) void*)g,
        (__attribute__((address_space(3))) void*)l, 16, 0, 0);
}
// 2^x on the TRANS pipe (v_exp_f32), no libm dependence.
__device__ __forceinline__ float exp2fast(float x) {
    return __builtin_amdgcn_exp2f(x);
}
// fast tanh: ~6 ops, 2 on TRANS pipe. |err| ~1e-6, invisible under f16.
__device__ __forceinline__ float fast_tanh(float x) {
    float xc = fminf(fmaxf(x, -9.f), 9.f);
    float t = exp2fast(xc * 2.88539008178f);   // e^(2x) = 2^(2x*log2e)
    return (t - 1.f) * __builtin_amdgcn_rcpf(t + 1.f);
}
// pack two f32 -> two f16 in one u32 (v_cvt_pkrtz_f16_f32)
__device__ __forceinline__ uint32_t pk16(float a, float b) {
    auto h2 = __builtin_amdgcn_cvt_pkrtz(a, b);
    return __builtin_bit_cast(uint32_t, h2);
}

// ---------------- K0: fused weight repack + xph = f16(x+pos) ----------------
__global__ __launch_bounds__(256) void prep(
        const float* __restrict__ x, const float* __restrict__ pos,
        const float* __restrict__ Wq, const float* __restrict__ Wk,
        const float* __restrict__ Wv, const float* __restrict__ Wo,
        _Float16* __restrict__ wqkv, _Float16* __restrict__ woh,
        _Float16* __restrict__ xph) {
    int bid = blockIdx.x;
    if (bid < 2048) {
        int idx = bid * 256 + threadIdx.x;
        if (idx < 1536 * 256) {
            int n = idx >> 8, e = idx & 255;
            int s = n >> 9, h = (n >> 6) & 7, d = n & 63;
            const float* W = (s == 0) ? Wq : (s == 1) ? Wk : Wv;
            wqkv[idx] = (_Float16)W[(h * NE + e) * ND + d];
        } else {
            int j = idx - 1536 * 256;
            int e = j >> 9, f = j & 511;
            woh[j] = (_Float16)Wo[f * NE + e];
        }
    } else {
        int i = ((bid - 2048) * 256 + threadIdx.x) * 4;
        float4 xv = *(const float4*)(x + i);
        float4 pv = *(const float4*)(pos + (i & (NL * NE - 1)));
        half4 o;
        o[0] = (_Float16)(xv.x + pv.x);
        o[1] = (_Float16)(xv.y + pv.y);
        o[2] = (_Float16)(xv.z + pv.z);
        o[3] = (_Float16)(xv.w + pv.w);
        *(half4*)(xph + i) = o;
    }
}

// ---------------- K1: fully-fused QKV projection + flash attention ----------
// One block per (b,h); 512 threads (8 waves); K/V panels resident in LDS.
// Phase A: Q/K/V = tanh(xph @ W) via 16 staged sub-GEMMs (X + 3W staged in
//   the unused K-panel area; acc in regs; T12 pack -> swizzled panels).
// Phase B: barrier-free flash attention over the resident panels; each wave
//   owns 64 q rows (2x32), in-register softmax, defer-max, permlane PV.
// Grid: 256 = 8 XCD x 32, b-major per XCD (xph panel L2-local).
__global__ __launch_bounds__(512, 2) void attn_fused(
        const _Float16* __restrict__ wqkv, const _Float16* __restrict__ xph,
        _Float16* __restrict__ attn_out) {
    __shared__ _Float16 Kp[512 * 64];    // [key][d], u^=(key&7); alias: staging
    __shared__ _Float16 Vtp[64 * 512];   // [d][key], u^=(d&7);  alias: Q scratch
    _Float16* Xs = Kp;                   // staging X [128][64]  (16 KB)
    _Float16* Ws = Kp + 128 * 64;        // staging W 3x[64][64] (24 KB)
    _Float16* Qs = Vtp;                  // Q panel scratch [512][64]

    int tid = threadIdx.x;
    int w8 = tid >> 6, l = tid & 63;
    int l31 = l & 31, hi = l >> 5;
    int rt = w8 & 3, d2w = w8 >> 2;
    int g0 = ((blockIdx.x & 7) << 5) + (blockIdx.x >> 3);
    int h = g0 & 7, b = g0 >> 3;
    const float C1 = 0.125f * 1.44269504089f;

    int lrow8 = l >> 3;
    int kc16 = (l & 7) ^ lrow8;          // pre-swizzled global 16B k-unit
    const _Float16* xg = xph + (size_t)(b * NL) * 256;
    const _Float16* wg = wqkv + (size_t)(h * 64) * 256;  // Q rows; +512/1024*256 for K/V

    // ---- Phase A: projections. wave role: rows rt*32 (+r*128), d-half d2w.
    f32x16 acc_q[4] = {}, acc_k[4] = {}, acc_v[4] = {};
    for (int kt2 = 0; kt2 < 4; ++kt2) {
#pragma unroll
        for (int r = 0; r < 4; ++r) {
#pragma unroll
            for (int i = 0; i < 2; ++i) {          // X rows r*128..+127, 64-k slice
                int c = w8 * 2 + i;
                int row = c * 8 + lrow8;
                cp16_g2l(xg + (size_t)(r * 128 + row) * 256 + kt2 * 64 + kc16 * 8,
                         Xs + c * 512);
            }
            if (r == 0) {                           // W q/k/v, 64-k slice
                int row = w8 * 8 + lrow8;
#pragma unroll
                for (int s = 0; s < 3; ++s)
                    cp16_g2l(wg + (size_t)s * 512 * 256 + (size_t)row * 256 + kt2 * 64 + kc16 * 8,
                             Ws + s * 4096 + w8 * 512);
            }
            __syncthreads();
#pragma unroll
            for (int ks2 = 0; ks2 < 4; ++ks2) {
                int rowb = rt * 32 + l31;
                half8 bf = *(const half8*)(Xs + rowb * 64 + (((ks2 * 2 + hi) ^ (rowb & 7)) << 3));
                int rowa = d2w * 32 + l31;
                int sa = rowa * 64 + (((ks2 * 2 + hi) ^ (rowa & 7)) << 3);
                half8 aq = *(const half8*)(Ws + sa);
                half8 ak = *(const half8*)(Ws + 4096 + sa);
                half8 av = *(const half8*)(Ws + 8192 + sa);
                acc_q[r] = mfma32(aq, bf, acc_q[r]);    // lane=q,   regs=d
                acc_k[r] = mfma32(ak, bf, acc_k[r]);    // lane=key, regs=d
                acc_v[r] = mfma32(bf, av, acc_v[r]);    // lane=d,   regs=key
            }
            __syncthreads();
        }
    }

    // ---- pack + tanh -> Qs (Vtp area) and Kp (staging done, safe) ----
#pragma unroll
    for (int r = 0; r < 4; ++r) {
        uint32_t cq[4][2], ck[4][2];
#pragma unroll
        for (int a = 0; a < 4; ++a)
#pragma unroll
            for (int p = 0; p < 2; ++p) {
                cq[a][p] = pk16(fast_tanh(acc_q[r][4 * a + 2 * p]),
                                fast_tanh(acc_q[r][4 * a + 2 * p + 1]));
                ck[a][p] = pk16(fast_tanh(acc_k[r][4 * a + 2 * p]),
                                fast_tanh(acc_k[r][4 * a + 2 * p + 1]));
            }
        int rowq = r * 128 + rt * 32 + l31;      // q or key row
#pragma unroll
        for (int ks = 0; ks < 2; ++ks) {
            u32x2 q0 = __builtin_amdgcn_permlane32_swap(cq[2 * ks][0], cq[2 * ks + 1][0], false, false);
            u32x2 q1 = __builtin_amdgcn_permlane32_swap(cq[2 * ks][1], cq[2 * ks + 1][1], false, false);
            u32x2 k0 = __builtin_amdgcn_permlane32_swap(ck[2 * ks][0], ck[2 * ks + 1][0], false, false);
            u32x2 k1 = __builtin_amdgcn_permlane32_swap(ck[2 * ks][1], ck[2 * ks + 1][1], false, false);
            union { uint32_t u[4]; half8 h8; } pq, pk;
            pq.u[0] = q0[0]; pq.u[1] = q1[0]; pq.u[2] = q0[1]; pq.u[3] = q1[1];
            pk.u[0] = k0[0]; pk.u[1] = k1[0]; pk.u[2] = k0[1]; pk.u[3] = k1[1];
            int uu = d2w * 4 + ks * 2 + hi;      // d-unit
            *(half8*)(Qs + rowq * 64 + ((uu ^ (rowq & 7)) << 3)) = pq.h8;
            *(half8*)(Kp + rowq * 64 + ((uu ^ (rowq & 7)) << 3)) = pk.h8;
        }
    }
    __syncthreads();
    // reload qf in attention assignment: wave w8 owns q rows w8*64..+63
    half8 qf[2][4];
#pragma unroll
    for (int qs = 0; qs < 2; ++qs)
#pragma unroll
        for (int ks = 0; ks < 4; ++ks) {
            int q = w8 * 64 + qs * 32 + l31;
            qf[qs][ks] = *(const half8*)(Qs + q * 64 + (((ks * 2 + hi) ^ (q & 7)) << 3));
        }
    __syncthreads();
    // ---- write Vtp (overwrites Qs) ----
#pragma unroll
    for (int r = 0; r < 4; ++r) {
        uint32_t cv[4][2];
#pragma unroll
        for (int a = 0; a < 4; ++a)
#pragma unroll
            for (int p = 0; p < 2; ++p)
                cv[a][p] = pk16(fast_tanh(acc_v[r][4 * a + 2 * p]),
                                fast_tanh(acc_v[r][4 * a + 2 * p + 1]));
        int d = d2w * 32 + l31;
#pragma unroll
        for (int ks = 0; ks < 2; ++ks) {
            u32x2 v0 = __builtin_amdgcn_permlane32_swap(cv[2 * ks][0], cv[2 * ks + 1][0], false, false);
            u32x2 v1 = __builtin_amdgcn_permlane32_swap(cv[2 * ks][1], cv[2 * ks + 1][1], false, false);
            union { uint32_t u[4]; half8 h8; } pv;
            pv.u[0] = v0[0]; pv.u[1] = v1[0]; pv.u[2] = v0[1]; pv.u[3] = v1[1];
            int uu = r * 16 + rt * 4 + ks * 2 + hi;   // key-unit (0..63)
            *(half8*)(Vtp + d * 512 + ((uu ^ (d & 7)) << 3)) = pv.h8;
        }
    }
    __syncthreads();

    // ---- Phase B: barrier-free flash attention over resident panels ----
    f32x16 acc_o[2][2] = {};
    float mrow[2] = {-1e30f, -1e30f}, lrow[2] = {0.f, 0.f};
    for (int kt = 0; kt < 8; ++kt) {
#pragma unroll
        for (int qs = 0; qs < 2; ++qs) {
            f32x16 acc_s[2] = {};
            __builtin_amdgcn_s_setprio(1);
#pragma unroll
            for (int ks = 0; ks < 4; ++ks)
#pragma unroll
                for (int kb2 = 0; kb2 < 2; ++kb2) {
                    int key = kt * 64 + kb2 * 32 + l31;
                    half8 kb = *(const half8*)(Kp + key * 64 + (((ks * 2 + hi) ^ (key & 7)) << 3));
                    acc_s[kb2] = mfma32(kb, qf[qs][ks], acc_s[kb2]);
                }
            __builtin_amdgcn_s_setprio(0);
            float mx = -1e30f;
#pragma unroll
            for (int kb2 = 0; kb2 < 2; ++kb2)
#pragma unroll
                for (int j = 0; j < 16; ++j) mx = fmaxf(mx, acc_s[kb2][j]);
            mx = fmaxf(mx, __shfl_xor(mx, 32));
            mx *= 0.125f;
            if (!__all(mx <= mrow[qs] + 8.f)) {
                float mn = fmaxf(mrow[qs], mx);
                float alpha = exp2fast((mrow[qs] - mn) * 1.44269504089f);
                mrow[qs] = mn;
                lrow[qs] *= alpha;
                float aq[16];
#pragma unroll
                for (int c = 0; c < 4; ++c)
#pragma unroll
                    for (int r = 0; r < 4; ++r)
                        aq[c * 4 + r] = __shfl(alpha, c * 8 + hi * 4 + r);
#pragma unroll
                for (int d2 = 0; d2 < 2; ++d2)
#pragma unroll
                    for (int j = 0; j < 16; ++j) acc_o[qs][d2][j] *= aq[j];
            }
            float ml = mrow[qs] * 1.44269504089f;
            float rs = 0.f;
            uint32_t cw[2][4][2];
#pragma unroll
            for (int kb2 = 0; kb2 < 2; ++kb2)
#pragma unroll
                for (int a = 0; a < 4; ++a)
#pragma unroll
                    for (int p = 0; p < 2; ++p) {
                        float p0 = exp2fast(fmaf(acc_s[kb2][4 * a + 2 * p],     C1, -ml));
                        float p1 = exp2fast(fmaf(acc_s[kb2][4 * a + 2 * p + 1], C1, -ml));
                        rs += p0 + p1;
                        cw[kb2][a][p] = pk16(p0, p1);
                    }
            rs += __shfl_xor(rs, 32);
            lrow[qs] += rs;
            __builtin_amdgcn_s_setprio(1);
#pragma unroll
            for (int ks = 0; ks < 4; ++ks) {
                int kb2 = ks >> 1, s = ks & 1;
                u32x2 r0 = __builtin_amdgcn_permlane32_swap(
                    cw[kb2][2 * s][0], cw[kb2][2 * s + 1][0], false, false);
                u32x2 r1 = __builtin_amdgcn_permlane32_swap(
                    cw[kb2][2 * s][1], cw[kb2][2 * s + 1][1], false, false);
                union { uint32_t u[4]; half8 h8; } pu;
                pu.u[0] = r0[0]; pu.u[1] = r1[0]; pu.u[2] = r0[1]; pu.u[3] = r1[1];
#pragma unroll
                for (int d2 = 0; d2 < 2; ++d2) {
                    int d = d2 * 32 + l31;
                    int uu = kt * 8 + ks * 2 + hi;
                    half8 vb = *(const half8*)(Vtp + d * 512 + ((uu ^ (d & 7)) << 3));
                    acc_o[qs][d2] = mfma32(pu.h8, vb, acc_o[qs][d2]);
                }
            }
            __builtin_amdgcn_s_setprio(0);
        }
    }
    // epilogue
#pragma unroll
    for (int qs = 0; qs < 2; ++qs) {
        size_t orow0 = (size_t)(b * NL + w8 * 64 + qs * 32);
#pragma unroll
        for (int c = 0; c < 4; ++c)
#pragma unroll
            for (int r = 0; r < 4; ++r) {
                int qrow = c * 8 + hi * 4 + r;
                float inv = 1.f / __shfl(lrow[qs], qrow);
#pragma unroll
                for (int d2 = 0; d2 < 2; ++d2)
                    attn_out[(orow0 + qrow) * NHD + h * ND + d2 * 32 + l31] =
                        (_Float16)(acc_o[qs][d2][c * 4 + r] * inv);
            }
    }
}

// ---------------- K2: output projection + f16 tanh residual ----------------
// tile 128e x 64m. BK=64, swizzled dbuf LDS, 2-phase pipeline.
// Grid: 512 = 8 XCD x (2 tn x 32 tm) -> attn B-panel fetched once per XCD.
__global__ __launch_bounds__(256) void final_gemm(
        const _Float16* __restrict__ woh, const _Float16* __restrict__ attn,
        const _Float16* __restrict__ xph, float* __restrict__ out) {
    __shared__ _Float16 Alds[2][128 * 64];
    __shared__ _Float16 Blds[2][64 * 64];
    int tid = threadIdx.x;
    int w = tid >> 6, l = tid & 63;
    int bid = blockIdx.x;
    int xcd = bid & 7, local = bid >> 3;   // 0..63
    int tn = local & 1;
    int tm = xcd * 32 + (local >> 1);
    int wn = w >> 1, wm = w & 1;
    int m16 = l & 15, g = l >> 4;
    int lrow8 = l >> 3;
    int kc16 = (l & 7) ^ lrow8;
    f32x4 acc[4][2] = {};

    const _Float16* Ag = woh + (size_t)tn * 128 * 512;
    const _Float16* Bg = attn + (size_t)tm * 64 * 512;

#define FIN_STAGE(kt, buf)                                                    \
    _Pragma("unroll") for (int i = 0; i < 4; ++i) {                           \
        int cA = w * 4 + i;                                                   \
        int row = cA * 8 + lrow8;                                             \
        cp16_g2l(Ag + (size_t)row * 512 + (kt) * 64 + kc16 * 8,               \
                 &Alds[buf][cA * 512]);                                       \
    }                                                                         \
    _Pragma("unroll") for (int i = 0; i < 2; ++i) {                           \
        int cB = w * 2 + i;                                                   \
        int row = cB * 8 + lrow8;                                             \
        cp16_g2l(Bg + (size_t)row * 512 + (kt) * 64 + kc16 * 8,               \
                 &Blds[buf][cB * 512]);                                       \
    }

    FIN_STAGE(0, 0);
    __syncthreads();
    int cur = 0;
    for (int kt = 0; kt < 8; ++kt) {
        if (kt < 7) { FIN_STAGE(kt + 1, cur ^ 1); }
#pragma unroll
        for (int ks = 0; ks < 2; ++ks) {
            half8 af[4], bf[2];
#pragma unroll
            for (int f = 0; f < 4; ++f) {
                int ra = wn * 64 + f * 16 + m16;
                af[f] = *(const half8*)(&Alds[cur][ra * 64 + (((ks * 4 + g) ^ (ra & 7)) << 3)]);
            }
#pragma unroll
            for (int f = 0; f < 2; ++f) {
                int rb = wm * 32 + f * 16 + m16;
                bf[f] = *(const half8*)(&Blds[cur][rb * 64 + (((ks * 4 + g) ^ (rb & 7)) << 3)]);
            }
#pragma unroll
            for (int nf = 0; nf < 4; ++nf)
#pragma unroll
                for (int mf = 0; mf < 2; ++mf)
                    acc[nf][mf] = mfma16(af[nf], bf[mf], acc[nf][mf]);
        }
        __syncthreads();
        cur ^= 1;
    }
#undef FIN_STAGE
#pragma unroll
    for (int nf = 0; nf < 4; ++nf) {
        int e = tn * 128 + wn * 64 + nf * 16 + g * 4;
#pragma unroll
        for (int mf = 0; mf < 2; ++mf) {
            int m = tm * 64 + wm * 32 + mf * 16 + m16;
            half4 hx = *(const half4*)(xph + (size_t)m * NE + e);
            f32x4 v = acc[nf][mf];
            float4 o;
            o.x = v[0] + fast_tanh((float)hx[0]);
            o.y = v[1] + fast_tanh((float)hx[1]);
            o.z = v[2] + fast_tanh((float)hx[2]);
            o.w = v[3] + fast_tanh((float)hx[3]);
            *(float4*)(out + (size_t)m * NE + e) = o;
        }
    }
}

extern "C" void kernel_launch(void* const* d_in, const int* in_sizes, int n_in,
                              void* d_out, int out_size, void* d_ws, size_t ws_size,
                              hipStream_t stream) {
    const float* x   = (const float*)d_in[0];
    const float* pos = (const float*)d_in[1];
    const float* Wq  = (const float*)d_in[2];
    const float* Wk  = (const float*)d_in[3];
    const float* Wv  = (const float*)d_in[4];
    const float* Wo  = (const float*)d_in[5];
    float* out = (float*)d_out;

    char* ws = (char*)d_ws;
    _Float16* xph   = (_Float16*)(ws);              //  8,388,608 B
    _Float16* wqkv  = (_Float16*)(ws + 8388608);    //    786,432 B
    _Float16* woh   = (_Float16*)(ws + 9175040);    //    262,144 B
    _Float16* attn  = (_Float16*)(ws + 9437184);    // 16,777,216 B

    prep<<<dim3(6144), dim3(256), 0, stream>>>(x, pos, Wq, Wk, Wv, Wo, wqkv, woh, xph);
    attn_fused<<<dim3(256), dim3(512), 0, stream>>>(wqkv, xph, attn);
    final_gemm<<<dim3(512), dim3(256), 0, stream>>>(woh, attn, xph, out);
}

// Round 15
// 72.040 us; speedup vs baseline: 1.3916x; 1.0318x over previous
//
#include <hip/hip_runtime.h>
#include <cstdint>

#define NB 32
#define NL 512
#define NE 256
#define NH 8
#define ND 64
#define NM 16384   // NB*NL
#define NHD 512    // NH*ND

using half8  = __attribute__((ext_vector_type(8))) _Float16;
using half4  = __attribute__((ext_vector_type(4))) _Float16;
using f32x4  = __attribute__((ext_vector_type(4))) float;
using f32x16 = __attribute__((ext_vector_type(16))) float;
using u32x2  = __attribute__((ext_vector_type(2))) unsigned int;

__device__ __forceinline__ f32x4 mfma16(half8 a, half8 b, f32x4 c) {
    return __builtin_amdgcn_mfma_f32_16x16x32_f16(a, b, c, 0, 0, 0);
}
__device__ __forceinline__ f32x16 mfma32(half8 a, half8 b, f32x16 c) {
    return __builtin_amdgcn_mfma_f32_32x32x16_f16(a, b, c, 0, 0, 0);
}
// async global->LDS, 16B/lane; LDS dest = wave-uniform base + lane*16.
__device__ __forceinline__ void cp16_g2l(const void* g, void* l) {
    __builtin_amdgcn_global_load_lds(
        (const __attribute__((address_space(1))) void*)g,
        (__attribute__((address_space(3))) void*)l, 16, 0, 0);
}
// 2^x on the TRANS pipe (v_exp_f32), no libm dependence.
__device__ __forceinline__ float exp2fast(float x) {
    return __builtin_amdgcn_exp2f(x);
}
// fast tanh: ~6 ops, 2 on TRANS pipe. |err| ~1e-6, invisible under f16.
__device__ __forceinline__ float fast_tanh(float x) {
    float xc = fminf(fmaxf(x, -9.f), 9.f);
    float t = exp2fast(xc * 2.88539008178f);   // e^(2x) = 2^(2x*log2e)
    return (t - 1.f) * __builtin_amdgcn_rcpf(t + 1.f);
}
// pack two f32 -> two f16 in one u32 (v_cvt_pkrtz_f16_f32)
__device__ __forceinline__ uint32_t pk16(float a, float b) {
    auto h2 = __builtin_amdgcn_cvt_pkrtz(a, b);
    return __builtin_bit_cast(uint32_t, h2);
}

// ---------------- K0: fused weight repack + xph = f16(x+pos) ----------------
__global__ __launch_bounds__(256) void prep(
        const float* __restrict__ x, const float* __restrict__ pos,
        const float* __restrict__ Wq, const float* __restrict__ Wk,
        const float* __restrict__ Wv, const float* __restrict__ Wo,
        _Float16* __restrict__ wqkv, _Float16* __restrict__ woh,
        _Float16* __restrict__ xph) {
    int bid = blockIdx.x;
    if (bid < 2048) {
        int idx = bid * 256 + threadIdx.x;
        if (idx < 1536 * 256) {
            int n = idx >> 8, e = idx & 255;
            int s = n >> 9, h = (n >> 6) & 7, d = n & 63;
            const float* W = (s == 0) ? Wq : (s == 1) ? Wk : Wv;
            wqkv[idx] = (_Float16)W[(h * NE + e) * ND + d];
        } else {
            int j = idx - 1536 * 256;
            int e = j >> 9, f = j & 511;
            woh[j] = (_Float16)Wo[f * NE + e];
        }
    } else {
        int i = ((bid - 2048) * 256 + threadIdx.x) * 4;
        float4 xv = *(const float4*)(x + i);
        float4 pv = *(const float4*)(pos + (i & (NL * NE - 1)));
        half4 o;
        o[0] = (_Float16)(xv.x + pv.x);
        o[1] = (_Float16)(xv.y + pv.y);
        o[2] = (_Float16)(xv.z + pv.z);
        o[3] = (_Float16)(xv.w + pv.w);
        *(half4*)(xph + i) = o;
    }
}

// ---------------- K1: fully-fused QKV projection + flash attention ----------
// One block per (b,h); 512 threads (8 waves); K/V panels resident in LDS.
// Phase A: Q/K/V = tanh(xph @ W) via 16 staged sub-GEMMs.
// Phase B: barrier-free attention; FIXED-BASE softmax: |s|<8 mathematically
//   (tanh-bounded q,k), so p = e^(s-4) needs NO online max -- no fmax chain,
//   no cross-lane max, no rescale. Softmax is shift-invariant => exact math.
// Grid: 256 = 8 XCD x 32, b-major per XCD (xph panel L2-local).
__global__ __launch_bounds__(512, 2) void attn_fused(
        const _Float16* __restrict__ wqkv, const _Float16* __restrict__ xph,
        _Float16* __restrict__ attn_out) {
    __shared__ _Float16 Kp[512 * 64];    // [key][d], u^=(key&7); alias: staging
    __shared__ _Float16 Vtp[64 * 512];   // [d][key], u^=(d&7);  alias: Q scratch
    _Float16* Xs = Kp;                   // staging X [128][64]  (16 KB)
    _Float16* Ws = Kp + 128 * 64;        // staging W 3x[64][64] (24 KB)
    _Float16* Qs = Vtp;                  // Q panel scratch [512][64]

    int tid = threadIdx.x;
    int w8 = tid >> 6, l = tid & 63;
    int l31 = l & 31, hi = l >> 5;
    int rt = w8 & 3, d2w = w8 >> 2;
    int g0 = ((blockIdx.x & 7) << 5) + (blockIdx.x >> 3);
    int h = g0 & 7, b = g0 >> 3;
    const float C1 = 0.125f * 1.44269504089f;   // scale * log2(e)
    const float C4 = 4.f * 1.44269504089f;      // fixed softmax base m=4

    int lrow8 = l >> 3;
    int kc16 = (l & 7) ^ lrow8;          // pre-swizzled global 16B k-unit
    const _Float16* xg = xph + (size_t)(b * NL) * 256;
    const _Float16* wg = wqkv + (size_t)(h * 64) * 256;  // Q rows; +512/1024*256 for K/V

    // ---- Phase A: projections. wave role: rows rt*32 (+r*128), d-half d2w.
    f32x16 acc_q[4] = {}, acc_k[4] = {}, acc_v[4] = {};
    for (int kt2 = 0; kt2 < 4; ++kt2) {
#pragma unroll
        for (int r = 0; r < 4; ++r) {
#pragma unroll
            for (int i = 0; i < 2; ++i) {          // X rows r*128..+127, 64-k slice
                int c = w8 * 2 + i;
                int row = c * 8 + lrow8;
                cp16_g2l(xg + (size_t)(r * 128 + row) * 256 + kt2 * 64 + kc16 * 8,
                         Xs + c * 512);
            }
            if (r == 0) {                           // W q/k/v, 64-k slice
                int row = w8 * 8 + lrow8;
#pragma unroll
                for (int s = 0; s < 3; ++s)
                    cp16_g2l(wg + (size_t)s * 512 * 256 + (size_t)row * 256 + kt2 * 64 + kc16 * 8,
                             Ws + s * 4096 + w8 * 512);
            }
            __syncthreads();
#pragma unroll
            for (int ks2 = 0; ks2 < 4; ++ks2) {
                int rowb = rt * 32 + l31;
                half8 bf = *(const half8*)(Xs + rowb * 64 + (((ks2 * 2 + hi) ^ (rowb & 7)) << 3));
                int rowa = d2w * 32 + l31;
                int sa = rowa * 64 + (((ks2 * 2 + hi) ^ (rowa & 7)) << 3);
                half8 aq = *(const half8*)(Ws + sa);
                half8 ak = *(const half8*)(Ws + 4096 + sa);
                half8 av = *(const half8*)(Ws + 8192 + sa);
                acc_q[r] = mfma32(aq, bf, acc_q[r]);    // lane=q,   regs=d
                acc_k[r] = mfma32(ak, bf, acc_k[r]);    // lane=key, regs=d
                acc_v[r] = mfma32(bf, av, acc_v[r]);    // lane=d,   regs=key
            }
            __syncthreads();
        }
    }

    // ---- pack + tanh -> Qs (Vtp area) and Kp (staging done, safe) ----
#pragma unroll
    for (int r = 0; r < 4; ++r) {
        uint32_t cq[4][2], ck[4][2];
#pragma unroll
        for (int a = 0; a < 4; ++a)
#pragma unroll
            for (int p = 0; p < 2; ++p) {
                cq[a][p] = pk16(fast_tanh(acc_q[r][4 * a + 2 * p]),
                                fast_tanh(acc_q[r][4 * a + 2 * p + 1]));
                ck[a][p] = pk16(fast_tanh(acc_k[r][4 * a + 2 * p]),
                                fast_tanh(acc_k[r][4 * a + 2 * p + 1]));
            }
        int rowq = r * 128 + rt * 32 + l31;      // q or key row
#pragma unroll
        for (int ks = 0; ks < 2; ++ks) {
            u32x2 q0 = __builtin_amdgcn_permlane32_swap(cq[2 * ks][0], cq[2 * ks + 1][0], false, false);
            u32x2 q1 = __builtin_amdgcn_permlane32_swap(cq[2 * ks][1], cq[2 * ks + 1][1], false, false);
            u32x2 k0 = __builtin_amdgcn_permlane32_swap(ck[2 * ks][0], ck[2 * ks + 1][0], false, false);
            u32x2 k1 = __builtin_amdgcn_permlane32_swap(ck[2 * ks][1], ck[2 * ks + 1][1], false, false);
            union { uint32_t u[4]; half8 h8; } pq, pk;
            pq.u[0] = q0[0]; pq.u[1] = q1[0]; pq.u[2] = q0[1]; pq.u[3] = q1[1];
            pk.u[0] = k0[0]; pk.u[1] = k1[0]; pk.u[2] = k0[1]; pk.u[3] = k1[1];
            int uu = d2w * 4 + ks * 2 + hi;      // d-unit
            *(half8*)(Qs + rowq * 64 + ((uu ^ (rowq & 7)) << 3)) = pq.h8;
            *(half8*)(Kp + rowq * 64 + ((uu ^ (rowq & 7)) << 3)) = pk.h8;
        }
    }
    __syncthreads();
    // reload qf in attention assignment: wave w8 owns q rows w8*64..+63
    half8 qf[2][4];
#pragma unroll
    for (int qs = 0; qs < 2; ++qs)
#pragma unroll
        for (int ks = 0; ks < 4; ++ks) {
            int q = w8 * 64 + qs * 32 + l31;
            qf[qs][ks] = *(const half8*)(Qs + q * 64 + (((ks * 2 + hi) ^ (q & 7)) << 3));
        }
    __syncthreads();
    // ---- write Vtp (overwrites Qs) ----
#pragma unroll
    for (int r = 0; r < 4; ++r) {
        uint32_t cv[4][2];
#pragma unroll
        for (int a = 0; a < 4; ++a)
#pragma unroll
            for (int p = 0; p < 2; ++p)
                cv[a][p] = pk16(fast_tanh(acc_v[r][4 * a + 2 * p]),
                                fast_tanh(acc_v[r][4 * a + 2 * p + 1]));
        int d = d2w * 32 + l31;
#pragma unroll
        for (int ks = 0; ks < 2; ++ks) {
            u32x2 v0 = __builtin_amdgcn_permlane32_swap(cv[2 * ks][0], cv[2 * ks + 1][0], false, false);
            u32x2 v1 = __builtin_amdgcn_permlane32_swap(cv[2 * ks][1], cv[2 * ks + 1][1], false, false);
            union { uint32_t u[4]; half8 h8; } pv;
            pv.u[0] = v0[0]; pv.u[1] = v1[0]; pv.u[2] = v0[1]; pv.u[3] = v1[1];
            int uu = r * 16 + rt * 4 + ks * 2 + hi;   // key-unit (0..63)
            *(half8*)(Vtp + d * 512 + ((uu ^ (d & 7)) << 3)) = pv.h8;
        }
    }
    __syncthreads();

    // ---- Phase B: attention, fixed-base softmax (no max tracking) ----
    f32x16 acc_o[2][2] = {};
    float lrow[2] = {0.f, 0.f};
    for (int kt = 0; kt < 8; ++kt) {
#pragma unroll
        for (int qs = 0; qs < 2; ++qs) {
            f32x16 acc_s[2] = {};
            __builtin_amdgcn_s_setprio(1);
#pragma unroll
            for (int ks = 0; ks < 4; ++ks)
#pragma unroll
                for (int kb2 = 0; kb2 < 2; ++kb2) {
                    int key = kt * 64 + kb2 * 32 + l31;
                    half8 kb = *(const half8*)(Kp + key * 64 + (((ks * 2 + hi) ^ (key & 7)) << 3));
                    acc_s[kb2] = mfma32(kb, qf[qs][ks], acc_s[kb2]);
                }
            __builtin_amdgcn_s_setprio(0);
            // p = 2^(s*C1 - C4) = e^(s/8 - 4);  |s/8| < 1*64/8 = 8 always.
            float rs = 0.f;
            uint32_t cw[2][4][2];
#pragma unroll
            for (int kb2 = 0; kb2 < 2; ++kb2)
#pragma unroll
                for (int a = 0; a < 4; ++a)
#pragma unroll
                    for (int p = 0; p < 2; ++p) {
                        float p0 = exp2fast(fmaf(acc_s[kb2][4 * a + 2 * p],     C1, -C4));
                        float p1 = exp2fast(fmaf(acc_s[kb2][4 * a + 2 * p + 1], C1, -C4));
                        rs += p0 + p1;
                        cw[kb2][a][p] = pk16(p0, p1);
                    }
            lrow[qs] += rs;
            __builtin_amdgcn_s_setprio(1);
#pragma unroll
            for (int ks = 0; ks < 4; ++ks) {
                int kb2 = ks >> 1, s = ks & 1;
                u32x2 r0 = __builtin_amdgcn_permlane32_swap(
                    cw[kb2][2 * s][0], cw[kb2][2 * s + 1][0], false, false);
                u32x2 r1 = __builtin_amdgcn_permlane32_swap(
                    cw[kb2][2 * s][1], cw[kb2][2 * s + 1][1], false, false);
                union { uint32_t u[4]; half8 h8; } pu;
                pu.u[0] = r0[0]; pu.u[1] = r1[0]; pu.u[2] = r0[1]; pu.u[3] = r1[1];
#pragma unroll
                for (int d2 = 0; d2 < 2; ++d2) {
                    int d = d2 * 32 + l31;
                    int uu = kt * 8 + ks * 2 + hi;
                    half8 vb = *(const half8*)(Vtp + d * 512 + ((uu ^ (d & 7)) << 3));
                    acc_o[qs][d2] = mfma32(pu.h8, vb, acc_o[qs][d2]);
                }
            }
            __builtin_amdgcn_s_setprio(0);
        }
    }
    // epilogue: lrow is split across hi halves -> combine, then divide.
#pragma unroll
    for (int qs = 0; qs < 2; ++qs) {
        lrow[qs] += __shfl_xor(lrow[qs], 32);
        size_t orow0 = (size_t)(b * NL + w8 * 64 + qs * 32);
#pragma unroll
        for (int c = 0; c < 4; ++c)
#pragma unroll
            for (int r = 0; r < 4; ++r) {
                int qrow = c * 8 + hi * 4 + r;
                float inv = 1.f / __shfl(lrow[qs], qrow);
#pragma unroll
                for (int d2 = 0; d2 < 2; ++d2)
                    attn_out[(orow0 + qrow) * NHD + h * ND + d2 * 32 + l31] =
                        (_Float16)(acc_o[qs][d2][c * 4 + r] * inv);
            }
    }
}

// ---------------- K2: output projection + f16 tanh residual ----------------
// tile 128e x 64m. BK=64, swizzled dbuf LDS, 2-phase pipeline.
// Grid: 512 = 8 XCD x (2 tn x 32 tm) -> attn B-panel fetched once per XCD.
__global__ __launch_bounds__(256) void final_gemm(
        const _Float16* __restrict__ woh, const _Float16* __restrict__ attn,
        const _Float16* __restrict__ xph, float* __restrict__ out) {
    __shared__ _Float16 Alds[2][128 * 64];
    __shared__ _Float16 Blds[2][64 * 64];
    int tid = threadIdx.x;
    int w = tid >> 6, l = tid & 63;
    int bid = blockIdx.x;
    int xcd = bid & 7, local = bid >> 3;   // 0..63
    int tn = local & 1;
    int tm = xcd * 32 + (local >> 1);
    int wn = w >> 1, wm = w & 1;
    int m16 = l & 15, g = l >> 4;
    int lrow8 = l >> 3;
    int kc16 = (l & 7) ^ lrow8;
    f32x4 acc[4][2] = {};

    const _Float16* Ag = woh + (size_t)tn * 128 * 512;
    const _Float16* Bg = attn + (size_t)tm * 64 * 512;

#define FIN_STAGE(kt, buf)                                                    \
    _Pragma("unroll") for (int i = 0; i < 4; ++i) {                           \
        int cA = w * 4 + i;                                                   \
        int row = cA * 8 + lrow8;                                             \
        cp16_g2l(Ag + (size_t)row * 512 + (kt) * 64 + kc16 * 8,               \
                 &Alds[buf][cA * 512]);                                       \
    }                                                                         \
    _Pragma("unroll") for (int i = 0; i < 2; ++i) {                           \
        int cB = w * 2 + i;                                                   \
        int row = cB * 8 + lrow8;                                             \
        cp16_g2l(Bg + (size_t)row * 512 + (kt) * 64 + kc16 * 8,               \
                 &Blds[buf][cB * 512]);                                       \
    }

    FIN_STAGE(0, 0);
    __syncthreads();
    int cur = 0;
    for (int kt = 0; kt < 8; ++kt) {
        if (kt < 7) { FIN_STAGE(kt + 1, cur ^ 1); }
#pragma unroll
        for (int ks = 0; ks < 2; ++ks) {
            half8 af[4], bf[2];
#pragma unroll
            for (int f = 0; f < 4; ++f) {
                int ra = wn * 64 + f * 16 + m16;
                af[f] = *(const half8*)(&Alds[cur][ra * 64 + (((ks * 4 + g) ^ (ra & 7)) << 3)]);
            }
#pragma unroll
            for (int f = 0; f < 2; ++f) {
                int rb = wm * 32 + f * 16 + m16;
                bf[f] = *(const half8*)(&Blds[cur][rb * 64 + (((ks * 4 + g) ^ (rb & 7)) << 3)]);
            }
#pragma unroll
            for (int nf = 0; nf < 4; ++nf)
#pragma unroll
                for (int mf = 0; mf < 2; ++mf)
                    acc[nf][mf] = mfma16(af[nf], bf[mf], acc[nf][mf]);
        }
        __syncthreads();
        cur ^= 1;
    }
#undef FIN_STAGE
#pragma unroll
    for (int nf = 0; nf < 4; ++nf) {
        int e = tn * 128 + wn * 64 + nf * 16 + g * 4;
#pragma unroll
        for (int mf = 0; mf < 2; ++mf) {
            int m = tm * 64 + wm * 32 + mf * 16 + m16;
            half4 hx = *(const half4*)(xph + (size_t)m * NE + e);
            f32x4 v = acc[nf][mf];
            float4 o;
            o.x = v[0] + fast_tanh((float)hx[0]);
            o.y = v[1] + fast_tanh((float)hx[1]);
            o.z = v[2] + fast_tanh((float)hx[2]);
            o.w = v[3] + fast_tanh((float)hx[3]);
            *(float4*)(out + (size_t)m * NE + e) = o;
        }
    }
}

extern "C" void kernel_launch(void* const* d_in, const int* in_sizes, int n_in,
                              void* d_out, int out_size, void* d_ws, size_t ws_size,
                              hipStream_t stream) {
    const float* x   = (const float*)d_in[0];
    const float* pos = (const float*)d_in[1];
    const float* Wq  = (const float*)d_in[2];
    const float* Wk  = (const float*)d_in[3];
    const float* Wv  = (const float*)d_in[4];
    const float* Wo  = (const float*)d_in[5];
    float* out = (float*)d_out;

    char* ws = (char*)d_ws;
    _Float16* xph   = (_Float16*)(ws);              //  8,388,608 B
    _Float16* wqkv  = (_Float16*)(ws + 8388608);    //    786,432 B
    _Float16* woh   = (_Float16*)(ws + 9175040);    //    262,144 B
    _Float16* attn  = (_Float16*)(ws + 9437184);    // 16,777,216 B

    prep<<<dim3(6144), dim3(256), 0, stream>>>(x, pos, Wq, Wk, Wv, Wo, wqkv, woh, xph);
    attn_fused<<<dim3(256), dim3(512), 0, stream>>>(wqkv, xph, attn);
    final_gemm<<<dim3(512), dim3(256), 0, stream>>>(woh, attn, xph, out);
}